// Round 1
// baseline (2881.982 us; speedup 1.0000x reference)
//
#include <hip/hip_runtime.h>
#include <math.h>

// Problem constants
#define NH 16
#define S_LEN 1024
#define DK 64
#define D_MODEL 1024
#define QKV_STRIDE 8388608   // B*NH*S*DK = 8*16*1024*64

// ---------------------------------------------------------------------------
// Tiled fp32 GEMM: C = A[M,K] @ B[K,N] + bias[N]
// 64x64 tile, BK=16, 256 threads, 4x4 register micro-tile per thread.
// QKV=1: scatter output into q/k/v buffers laid out [B*NH, S, DK].
// ---------------------------------------------------------------------------
template<int QKV>
__global__ __launch_bounds__(256)
void gemm_kernel(const float* __restrict__ A, const float* __restrict__ Bm,
                 const float* __restrict__ bias, float* __restrict__ C,
                 int M, int N, int K) {
    __shared__ float As[16][65];   // transposed A tile: As[k][m]
    __shared__ float Bs[16][65];   // Bs[k][n]
    const int t  = threadIdx.x;
    const int tx = t & 15, ty = t >> 4;
    const int row0 = blockIdx.y * 64;
    const int col0 = blockIdx.x * 64;

    float acc[4][4] = {};

    for (int k0 = 0; k0 < K; k0 += 16) {
        // Load A tile (64 rows x 16 k) as float4, store transposed
        {
            const int r  = t >> 2;          // 0..63
            const int c4 = (t & 3) * 4;     // 0,4,8,12
            const float4 av = *reinterpret_cast<const float4*>(
                &A[(size_t)(row0 + r) * K + k0 + c4]);
            As[c4 + 0][r] = av.x; As[c4 + 1][r] = av.y;
            As[c4 + 2][r] = av.z; As[c4 + 3][r] = av.w;
        }
        // Load B tile (16 k x 64 n) as float4
        {
            const int r  = t >> 4;          // 0..15
            const int c4 = (t & 15) * 4;    // 0..60
            const float4 bv = *reinterpret_cast<const float4*>(
                &Bm[(size_t)(k0 + r) * N + col0 + c4]);
            Bs[r][c4 + 0] = bv.x; Bs[r][c4 + 1] = bv.y;
            Bs[r][c4 + 2] = bv.z; Bs[r][c4 + 3] = bv.w;
        }
        __syncthreads();

        #pragma unroll
        for (int kk = 0; kk < 16; ++kk) {
            float a[4], b[4];
            #pragma unroll
            for (int i = 0; i < 4; ++i) a[i] = As[kk][ty * 4 + i];
            #pragma unroll
            for (int j = 0; j < 4; ++j) b[j] = Bs[kk][tx * 4 + j];
            #pragma unroll
            for (int i = 0; i < 4; ++i)
                #pragma unroll
                for (int j = 0; j < 4; ++j)
                    acc[i][j] += a[i] * b[j];
        }
        __syncthreads();
    }

    // Epilogue: add bias, write out
    #pragma unroll
    for (int i = 0; i < 4; ++i) {
        const int m = row0 + ty * 4 + i;
        #pragma unroll
        for (int j = 0; j < 4; ++j) {
            const int n = col0 + tx * 4 + j;
            const float v = acc[i][j] + bias[n];
            if (QKV) {
                // n in [0,3072): which = q/k/v, then head h, dim d
                const int which = n >> 10;
                const int h = (n & 1023) >> 6;
                const int d = n & 63;
                const int b = m >> 10;
                const int s = m & 1023;
                C[(size_t)which * QKV_STRIDE +
                  (((size_t)(b * NH + h)) * S_LEN + s) * DK + d] = v;
            } else {
                C[(size_t)m * N + n] = v;
            }
        }
    }
}

// ---------------------------------------------------------------------------
// Attention: one workgroup (256 threads) per (b,h, 8-query-row block).
// Scores for the 8 rows staged in LDS; relative-position terms collapsed:
//   score += qrel[r][clip(j-i,-16,16)+16]  (only indices 0..16 under causality)
//   out    += per-bin attention sums @ lut_v, where bins 1..16 are single
//             taps p[i-16+t] and bin 0 = rowsum - sum(taps).
// ---------------------------------------------------------------------------
__global__ __launch_bounds__(256)
void attn_kernel(const float* __restrict__ qkv,
                 const float* __restrict__ lut_k,
                 const float* __restrict__ lut_v,
                 float* __restrict__ ao) {
    const float* qb = qkv;
    const float* kb = qkv + QKV_STRIDE;
    const float* vb = qkv + 2 * (size_t)QKV_STRIDE;

    const int blk = blockIdx.x;
    const int nib = S_LEN / 8;          // 128 row-blocks per (b,h)
    const int ib  = blk % nib;
    const int bh  = blk / nib;          // b*16 + h
    const int b   = bh >> 4, h = bh & 15;
    const int i0  = ib * 8;
    const int t   = threadIdx.x;

    __shared__ float sc[8][S_LEN];      // 32 KB: scores -> p values
    __shared__ float qs[8][DK];         // 2 KB
    __shared__ float kt[64][DK + 1];    // 16.25 KB (k tile, reused for v)
    __shared__ float lk[17][DK];        // 4.25 KB
    __shared__ float lv[17][DK];        // 4.25 KB
    __shared__ float qrel[8][17];
    __shared__ float rowsum[8];

    const float* qp = qb + (size_t)bh * S_LEN * DK;
    const float* kp = kb + (size_t)bh * S_LEN * DK;
    const float* vp = vb + (size_t)bh * S_LEN * DK;

    // ---- phase 0: load q rows, LUTs ----
    for (int e = t; e < 8 * DK; e += 256)
        qs[e >> 6][e & 63] = qp[(size_t)(i0 + (e >> 6)) * DK + (e & 63)];
    for (int e = t; e < 17 * DK; e += 256) {
        lk[e >> 6][e & 63] = lut_k[e];
        lv[e >> 6][e & 63] = lut_v[e];
    }
    __syncthreads();

    if (t < 8 * 17) {
        const int r = t / 17, tt = t % 17;
        float s = 0.f;
        #pragma unroll
        for (int d = 0; d < DK; ++d) s += qs[r][d] * lk[tt][d];
        qrel[r][tt] = s;
    }
    __syncthreads();

    const int jmax = i0 + 7;
    const int NT = (jmax >> 6) + 1;     // number of 64-wide j tiles

    // ---- phase 1: scores ----
    for (int tile = 0; tile < NT; ++tile) {
        const int j0 = tile << 6;
        for (int e = t; e < 64 * 64; e += 256)
            kt[e >> 6][e & 63] = kp[(size_t)(j0 + (e >> 6)) * DK + (e & 63)];
        __syncthreads();

        for (int p = t; p < 8 * 64; p += 256) {
            const int r = p >> 6, jj = p & 63;
            const int i = i0 + r, j = j0 + jj;
            float s;
            if (j > i) {
                s = -INFINITY;
            } else {
                float dot = 0.f;
                #pragma unroll
                for (int d = 0; d < DK; ++d) dot += qs[r][d] * kt[jj][d];
                int t17 = j - i + 16;
                if (t17 < 0) t17 = 0;
                s = (dot + qrel[r][t17]) * 0.125f;
            }
            sc[r][j] = s;
        }
        __syncthreads();
    }

    // ---- phase 2: softmax (keep unnormalized p, stash rowsum) ----
    {
        const int r = t >> 5, g = t & 31;
        const int n = NT << 6;
        float m = -INFINITY;
        for (int j = g; j < n; j += 32) m = fmaxf(m, sc[r][j]);
        #pragma unroll
        for (int mask = 16; mask; mask >>= 1)
            m = fmaxf(m, __shfl_xor(m, mask, 32));
        float sum = 0.f;
        for (int j = g; j < n; j += 32) {
            const float p = __expf(sc[r][j] - m);   // exp(-inf)=0 for masked
            sc[r][j] = p;
            sum += p;
        }
        #pragma unroll
        for (int mask = 16; mask; mask >>= 1)
            sum += __shfl_xor(sum, mask, 32);
        if (g == 0) rowsum[r] = sum;
    }
    __syncthreads();

    // ---- phase 3: PV (p @ v), v tiles through kt ----
    float acc0 = 0.f, acc1 = 0.f;
    const int r_lo = t >> 6;            // 0..3
    const int d    = t & 63;
    for (int tile = 0; tile < NT; ++tile) {
        const int j0 = tile << 6;
        for (int e = t; e < 64 * 64; e += 256)
            kt[e >> 6][e & 63] = vp[(size_t)(j0 + (e >> 6)) * DK + (e & 63)];
        __syncthreads();

        #pragma unroll
        for (int jj = 0; jj < 64; ++jj) acc0 += sc[r_lo][j0 + jj] * kt[jj][d];
        const int r_hi = r_lo + 4;
        #pragma unroll
        for (int jj = 0; jj < 64; ++jj) acc1 += sc[r_hi][j0 + jj] * kt[jj][d];
        __syncthreads();
    }

    // ---- phase 4: relative-position V taps + normalize + write ----
    #pragma unroll 1
    for (int pass = 0; pass < 2; ++pass) {
        const int rr = r_lo + pass * 4;
        float acc = pass ? acc1 : acc0;
        const int i = i0 + rr;
        float c0 = rowsum[rr];
        #pragma unroll
        for (int tt = 1; tt <= 16; ++tt) {
            const int j = i - 16 + tt;
            if (j >= 0) {
                const float pj = sc[rr][j];
                acc += pj * lv[tt][d];
                c0 -= pj;
            }
        }
        acc += c0 * lv[0][d];           // bin 0: all j <= i-16
        ao[((size_t)b * S_LEN + i) * D_MODEL + h * DK + d] = acc / rowsum[rr];
    }
}

// ---------------------------------------------------------------------------
extern "C" void kernel_launch(void* const* d_in, const int* in_sizes, int n_in,
                              void* d_out, int out_size, void* d_ws, size_t ws_size,
                              hipStream_t stream) {
    const float* x      = (const float*)d_in[0];
    const float* W_attn = (const float*)d_in[1];
    const float* b_attn = (const float*)d_in[2];
    const float* W_proj = (const float*)d_in[3];
    const float* b_proj = (const float*)d_in[4];
    const float* lut_k  = (const float*)d_in[5];
    const float* lut_v  = (const float*)d_in[6];
    float* out = (float*)d_out;

    float* qkv = (float*)d_ws;                       // 3 * QKV_STRIDE floats
    float* ao  = qkv + 3 * (size_t)QKV_STRIDE;       // B*S*D floats

    // 1) QKV projection: [8192,1024]@[1024,3072]+bias -> q/k/v [B*H,S,64]
    dim3 g1(3072 / 64, 8192 / 64);
    gemm_kernel<1><<<g1, 256, 0, stream>>>(x, W_attn, b_attn, qkv,
                                           8192, 3072, 1024);

    // 2) attention with relative-position K/V terms -> ao [B,S,D]
    attn_kernel<<<16384, 256, 0, stream>>>(qkv, lut_k, lut_v, ao);

    // 3) output projection: [8192,1024]@[1024,1024]+bias -> out
    dim3 g2(1024 / 64, 8192 / 64);
    gemm_kernel<0><<<g2, 256, 0, stream>>>(ao, W_proj, b_proj, out,
                                           8192, 1024, 1024);
}

// Round 2
// 1553.254 us; speedup vs baseline: 1.8554x; 1.8554x over previous
//
#include <hip/hip_runtime.h>
#include <hip/hip_bf16.h>
#include <math.h>

#define NH 16
#define S_LEN 1024
#define DK 64
#define D_MODEL 1024
#define QKV_STRIDE 8388608   // B*NH*S*DK

typedef __attribute__((ext_vector_type(8))) short bf16x8;
typedef __attribute__((ext_vector_type(4))) float f32x4;

__device__ __forceinline__ short f2b(float x) {
    union { __hip_bfloat16 h; short s; } u;
    u.h = __float2bfloat16(x);
    return u.s;
}

// ---------------------------------------------------------------------------
// Tiled fp32 GEMM (unchanged from R1): C = A[M,K] @ B[K,N] + bias[N]
// ---------------------------------------------------------------------------
template<int QKV>
__global__ __launch_bounds__(256)
void gemm_kernel(const float* __restrict__ A, const float* __restrict__ Bm,
                 const float* __restrict__ bias, float* __restrict__ C,
                 int M, int N, int K) {
    __shared__ float As[16][65];
    __shared__ float Bs[16][65];
    const int t  = threadIdx.x;
    const int tx = t & 15, ty = t >> 4;
    const int row0 = blockIdx.y * 64;
    const int col0 = blockIdx.x * 64;

    float acc[4][4] = {};

    for (int k0 = 0; k0 < K; k0 += 16) {
        {
            const int r  = t >> 2;
            const int c4 = (t & 3) * 4;
            const float4 av = *reinterpret_cast<const float4*>(
                &A[(size_t)(row0 + r) * K + k0 + c4]);
            As[c4 + 0][r] = av.x; As[c4 + 1][r] = av.y;
            As[c4 + 2][r] = av.z; As[c4 + 3][r] = av.w;
        }
        {
            const int r  = t >> 4;
            const int c4 = (t & 15) * 4;
            const float4 bv = *reinterpret_cast<const float4*>(
                &Bm[(size_t)(k0 + r) * N + col0 + c4]);
            Bs[r][c4 + 0] = bv.x; Bs[r][c4 + 1] = bv.y;
            Bs[r][c4 + 2] = bv.z; Bs[r][c4 + 3] = bv.w;
        }
        __syncthreads();

        #pragma unroll
        for (int kk = 0; kk < 16; ++kk) {
            float a[4], b[4];
            #pragma unroll
            for (int i = 0; i < 4; ++i) a[i] = As[kk][ty * 4 + i];
            #pragma unroll
            for (int j = 0; j < 4; ++j) b[j] = Bs[kk][tx * 4 + j];
            #pragma unroll
            for (int i = 0; i < 4; ++i)
                #pragma unroll
                for (int j = 0; j < 4; ++j)
                    acc[i][j] += a[i] * b[j];
        }
        __syncthreads();
    }

    #pragma unroll
    for (int i = 0; i < 4; ++i) {
        const int m = row0 + ty * 4 + i;
        #pragma unroll
        for (int j = 0; j < 4; ++j) {
            const int n = col0 + tx * 4 + j;
            const float v = acc[i][j] + bias[n];
            if (QKV) {
                const int which = n >> 10;
                const int h = (n & 1023) >> 6;
                const int d = n & 63;
                const int b = m >> 10;
                const int s = m & 1023;
                C[(size_t)which * QKV_STRIDE +
                  (((size_t)(b * NH + h)) * S_LEN + s) * DK + d] = v;
            } else {
                C[(size_t)m * N + n] = v;
            }
        }
    }
}

// ---------------------------------------------------------------------------
// MFMA flash attention with relative-position terms.
// Block = (b,h, 64 query rows); 4 waves x 16 rows; K/V tiles of 64 in LDS.
// mfma_f32_16x16x32_bf16: A lane: row=l&15, k=(l>>4)*8+i ; C/D: col=l&15,
// row=(l>>4)*4+reg (m89-verified).
// ---------------------------------------------------------------------------
__global__ __launch_bounds__(256, 4)
void attn_mfma_kernel(const float* __restrict__ qkv,
                      const float* __restrict__ lut_k,
                      const float* __restrict__ lut_v,
                      float* __restrict__ ao) {
    const int blk = blockIdx.x;
    const int ib = blk & 15;
    const int bh = blk >> 4;
    const int b = bh >> 4, h = bh & 15;
    const int i0 = ib * 64;
    const int t = threadIdx.x;
    const int w = t >> 6;
    const int lane = t & 63;
    const int g = lane >> 4;
    const int c = lane & 15;

    __shared__ __align__(16) char smem[37376];
    char* ktb = smem;                       // 8 KB  K tile bf16 [j=64][d=64], swz ((j&7)<<4)
    char* vtb = smem + 8192;                // 8 KB  V^T bf16 [d=64][j=64], swz (((d>>2)^d)&7)<<4
    char* pb  = smem + 16384;               // 8 KB  P per-wave [16][64] bf16, swz ((row&7)<<4)
    float* qrel  = (float*)(smem + 24576);          // [64][17]
    float* lvf   = (float*)(smem + 24576 + 4352);   // [17][64]
    float* tapss = (float*)(smem + 24576 + 8704);   // [64][16] tap scores
    // phase-0 temporaries (overlap ktb/vtb and pb):
    float* qf  = (float*)smem;              // [64][64] fp32 q block
    float* lkf = (float*)pb;                // [17][64] fp32 lut_k

    const float* qp = qkv + (size_t)bh * (S_LEN * DK);
    const float* kp = qp + QKV_STRIDE;
    const float* vp = qp + 2 * (size_t)QKV_STRIDE;

    // ---- phase 0: stage q (fp32), LUTs ----
    for (int f = t; f < 1024; f += 256) {
        const int row = f >> 4, c4 = (f & 15) * 4;
        *(float4*)&qf[row * 64 + c4] =
            *(const float4*)&qp[(size_t)(i0 + row) * DK + c4];
    }
    for (int e = t; e < 17 * 64; e += 256) {
        lkf[e] = lut_k[e];
        lvf[e] = lut_v[e];
    }
    __syncthreads();

    // qrel[r][tap] = q_row(i0+r) . lut_k[tap]   (rotated LDS reads)
    {
        const int r = t & 63;
        for (int tap = t >> 6; tap < 17; tap += 4) {
            float s = 0.f;
            for (int dd = 0; dd < 64; ++dd) {
                const int d = (dd + r) & 63;
                s += qf[r * 64 + d] * lkf[tap * 64 + d];
            }
            qrel[r * 17 + tap] = s;
        }
    }

    // Q fragments (bf16) from qf
    bf16x8 qa[2];
    {
        const int row = w * 16 + c;
        #pragma unroll
        for (int kh = 0; kh < 2; ++kh) {
            f32x4 lo = *(f32x4*)&qf[row * 64 + kh * 32 + g * 8];
            f32x4 hi = *(f32x4*)&qf[row * 64 + kh * 32 + g * 8 + 4];
            bf16x8 v;
            v[0] = f2b(lo[0]); v[1] = f2b(lo[1]); v[2] = f2b(lo[2]); v[3] = f2b(lo[3]);
            v[4] = f2b(hi[0]); v[5] = f2b(hi[1]); v[6] = f2b(hi[2]); v[7] = f2b(hi[3]);
            qa[kh] = v;
        }
    }
    __syncthreads();   // qf/lkf dead; ktb/vtb/pb free for tile loop

    f32x4 acc[4];
    #pragma unroll
    for (int dt = 0; dt < 4; ++dt) acc[dt] = (f32x4)0.f;
    float m_r[4], l_r[4];
    #pragma unroll
    for (int r = 0; r < 4; ++r) { m_r[r] = -INFINITY; l_r[r] = 0.f; }

    const int NT = ib + 1;
    for (int tile = 0; tile < NT; ++tile) {
        const int j0 = tile << 6;

        // ---- stage K and V^T (bf16) ----
        #pragma unroll
        for (int it = 0; it < 4; ++it) {
            const int f = it * 256 + t;
            const int row = f >> 4, c4 = (f & 15) * 4;
            const float4 kv4 = *(const float4*)&kp[(size_t)(j0 + row) * DK + c4];
            ushort4 kb4;
            kb4.x = (unsigned short)f2b(kv4.x);
            kb4.y = (unsigned short)f2b(kv4.y);
            kb4.z = (unsigned short)f2b(kv4.z);
            kb4.w = (unsigned short)f2b(kv4.w);
            unsigned kbyte = ((unsigned)row << 7) + ((unsigned)c4 << 1);
            kbyte ^= (unsigned)(row & 7) << 4;
            *(ushort4*)(ktb + kbyte) = kb4;

            const float4 vv4 = *(const float4*)&vp[(size_t)(j0 + row) * DK + c4];
            const float vsc[4] = { vv4.x, vv4.y, vv4.z, vv4.w };
            #pragma unroll
            for (int ww = 0; ww < 4; ++ww) {
                const int d = c4 + ww;
                unsigned vbyte = ((unsigned)d << 7) + ((unsigned)row << 1);
                vbyte ^= (unsigned)(((d >> 2) ^ d) & 7) << 4;
                *(short*)(vtb + vbyte) = f2b(vsc[ww]);
            }
        }
        __syncthreads();

        // ---- QK^T + score fixup ----
        float p[4][4];
        #pragma unroll
        for (int sub = 0; sub < 4; ++sub) {
            f32x4 s = (f32x4)0.f;
            const int krow = sub * 16 + c;
            #pragma unroll
            for (int kh = 0; kh < 2; ++kh) {
                unsigned byte = ((unsigned)krow << 7) + ((unsigned)kh << 6) + ((unsigned)g << 4);
                byte ^= (unsigned)(krow & 7) << 4;
                bf16x8 kb = *(bf16x8*)(ktb + byte);
                s = __builtin_amdgcn_mfma_f32_16x16x32_bf16(qa[kh], kb, s, 0, 0, 0);
            }
            const int dbase = (tile - ib) * 64 + (sub * 16 + c) - (w * 16 + g * 4);
            #pragma unroll
            for (int r = 0; r < 4; ++r) {
                const int dj = dbase - r;
                int t17 = dj + 16;
                t17 = t17 < 0 ? 0 : (t17 > 16 ? 16 : t17);
                const int il = w * 16 + g * 4 + r;
                float sc = (s[r] + qrel[il * 17 + t17]) * 0.125f;
                if (tile == ib && dj > 0) sc = -INFINITY;
                p[sub][r] = sc;
            }
        }

        // ---- capture tap scores (dj in [-15,0]) for epilogue V-term ----
        if (tile >= ib - 1) {
            #pragma unroll
            for (int sub = 0; sub < 4; ++sub) {
                const int dbase = (tile - ib) * 64 + (sub * 16 + c) - (w * 16 + g * 4);
                #pragma unroll
                for (int r = 0; r < 4; ++r) {
                    const int dj = dbase - r;
                    if (dj >= -15 && dj <= 0) {
                        const int il = w * 16 + g * 4 + r;
                        tapss[il * 16 + dj + 15] = p[sub][r];
                    }
                }
            }
        }

        // ---- online softmax (rows live in 16-lane groups) ----
        #pragma unroll
        for (int r = 0; r < 4; ++r) {
            float mx = fmaxf(fmaxf(p[0][r], p[1][r]), fmaxf(p[2][r], p[3][r]));
            #pragma unroll
            for (int msk = 1; msk < 16; msk <<= 1)
                mx = fmaxf(mx, __shfl_xor(mx, msk));
            const float mn = fmaxf(m_r[r], mx);
            const float scale = __expf(m_r[r] - mn);
            m_r[r] = mn;
            float sum = 0.f;
            #pragma unroll
            for (int sub = 0; sub < 4; ++sub) {
                const float pe = __expf(p[sub][r] - mn);
                p[sub][r] = pe;
                sum += pe;
            }
            #pragma unroll
            for (int msk = 1; msk < 16; msk <<= 1)
                sum += __shfl_xor(sum, msk);
            l_r[r] = l_r[r] * scale + sum;
            #pragma unroll
            for (int dt = 0; dt < 4; ++dt) acc[dt][r] *= scale;
        }

        // ---- P -> per-wave LDS (bf16, swizzled) ----
        char* pw = pb + w * 2048;
        #pragma unroll
        for (int sub = 0; sub < 4; ++sub)
            #pragma unroll
            for (int r = 0; r < 4; ++r) {
                const int row = g * 4 + r;
                unsigned byte = ((unsigned)row << 7) + (((unsigned)(sub * 16 + c)) << 1);
                byte ^= (unsigned)(row & 7) << 4;
                *(short*)(pw + byte) = f2b(p[sub][r]);
            }

        // ---- PV ----
        bf16x8 pa[2];
        #pragma unroll
        for (int jh = 0; jh < 2; ++jh) {
            unsigned byte = ((unsigned)c << 7) + ((unsigned)jh << 6) + ((unsigned)g << 4);
            byte ^= (unsigned)(c & 7) << 4;
            pa[jh] = *(bf16x8*)(pw + byte);
        }
        #pragma unroll
        for (int dt = 0; dt < 4; ++dt) {
            const int d = dt * 16 + c;
            #pragma unroll
            for (int jh = 0; jh < 2; ++jh) {
                unsigned byte = ((unsigned)d << 7) + ((unsigned)jh << 6) + ((unsigned)g << 4);
                byte ^= (unsigned)(((d >> 2) ^ d) & 7) << 4;
                bf16x8 vb = *(bf16x8*)(vtb + byte);
                acc[dt] = __builtin_amdgcn_mfma_f32_16x16x32_bf16(pa[jh], vb, acc[dt], 0, 0, 0);
            }
        }
        __syncthreads();
    }

    // ---- epilogue: taps + bin-0 residual + normalize + write ----
    const int rbase = w * 16 + g * 4;
    #pragma unroll
    for (int r = 0; r < 4; ++r) {
        const int il = rbase + r;
        const float mr = m_r[r];
        float c0 = l_r[r];
        float tp[16];
        #pragma unroll
        for (int tap = 0; tap < 16; ++tap) {
            const int jg = i0 + il + tap - 15;
            float pv = 0.f;
            if (jg >= 0) pv = __expf(tapss[il * 16 + tap] - mr);
            tp[tap] = pv;
            c0 -= pv;
        }
        const float invl = 1.f / l_r[r];
        #pragma unroll
        for (int dt = 0; dt < 4; ++dt) {
            const int d = dt * 16 + c;
            float o = acc[dt][r] + c0 * lvf[d];
            #pragma unroll
            for (int tap = 0; tap < 16; ++tap)
                o += tp[tap] * lvf[(tap + 1) * 64 + d];
            o *= invl;
            ao[((size_t)b * S_LEN + (i0 + il)) * D_MODEL + h * DK + d] = o;
        }
    }
}

// ---------------------------------------------------------------------------
extern "C" void kernel_launch(void* const* d_in, const int* in_sizes, int n_in,
                              void* d_out, int out_size, void* d_ws, size_t ws_size,
                              hipStream_t stream) {
    const float* x      = (const float*)d_in[0];
    const float* W_attn = (const float*)d_in[1];
    const float* b_attn = (const float*)d_in[2];
    const float* W_proj = (const float*)d_in[3];
    const float* b_proj = (const float*)d_in[4];
    const float* lut_k  = (const float*)d_in[5];
    const float* lut_v  = (const float*)d_in[6];
    float* out = (float*)d_out;

    float* qkv = (float*)d_ws;
    float* ao  = qkv + 3 * (size_t)QKV_STRIDE;

    dim3 g1(3072 / 64, 8192 / 64);
    gemm_kernel<1><<<g1, 256, 0, stream>>>(x, W_attn, b_attn, qkv,
                                           8192, 3072, 1024);

    attn_mfma_kernel<<<2048, 256, 0, stream>>>(qkv, lut_k, lut_v, ao);

    dim3 g2(1024 / 64, 8192 / 64);
    gemm_kernel<0><<<g2, 256, 0, stream>>>(ao, W_proj, b_proj, out,
                                           8192, 1024, 1024);
}

// Round 3
// 435.413 us; speedup vs baseline: 6.6190x; 3.5673x over previous
//
#include <hip/hip_runtime.h>
#include <hip/hip_bf16.h>
#include <math.h>

#define NH 16
#define S_LEN 1024
#define DK 64
#define D_MODEL 1024
#define HSZ 8388608          // B*NH*S*DK elements per q/k/v buffer

typedef __attribute__((ext_vector_type(8))) short bf16x8;
typedef __attribute__((ext_vector_type(4))) float f32x4;
typedef unsigned short USH;

__device__ __forceinline__ short f2b(float x) {
    union { __hip_bfloat16 h; short s; } u;
    u.h = __float2bfloat16(x);
    return u.s;
}

__device__ __forceinline__ void gload16(const void* src, void* lds) {
    __builtin_amdgcn_global_load_lds(
        (const __attribute__((address_space(1))) void*)src,
        (__attribute__((address_space(3))) void*)lds,
        16, 0, 0);
}

// ---------------------------------------------------------------------------
// fp32 -> bf16 conversion (exact-grid, 8 elems/thread)
// ---------------------------------------------------------------------------
__global__ __launch_bounds__(256)
void conv_bf16_kernel(const float* __restrict__ in, USH* __restrict__ out) {
    const int i = (blockIdx.x * 256 + threadIdx.x) * 8;
    const float4 a = *(const float4*)&in[i];
    const float4 b = *(const float4*)&in[i + 4];
    ushort4 o0, o1;
    o0.x = (USH)f2b(a.x); o0.y = (USH)f2b(a.y); o0.z = (USH)f2b(a.z); o0.w = (USH)f2b(a.w);
    o1.x = (USH)f2b(b.x); o1.y = (USH)f2b(b.y); o1.z = (USH)f2b(b.z); o1.w = (USH)f2b(b.w);
    *(ushort4*)&out[i] = o0;
    *(ushort4*)&out[i + 4] = o1;
}

// ---------------------------------------------------------------------------
// Transpose + convert: in [R][C] fp32 -> out [C][R] bf16. 64x64 tiles.
// ---------------------------------------------------------------------------
__global__ __launch_bounds__(256)
void transp_bf16_kernel(const float* __restrict__ in, USH* __restrict__ out,
                        int R, int C) {
    __shared__ USH Ts[64][65];
    const int r0 = blockIdx.y * 64, c0 = blockIdx.x * 64;
    const int tr = threadIdx.x >> 4;
    const int tc4 = (threadIdx.x & 15) * 4;
    #pragma unroll
    for (int ph = 0; ph < 4; ++ph) {
        const int r = ph * 16 + tr;
        const float4 v = *(const float4*)&in[(size_t)(r0 + r) * C + c0 + tc4];
        Ts[tc4 + 0][r] = (USH)f2b(v.x);
        Ts[tc4 + 1][r] = (USH)f2b(v.y);
        Ts[tc4 + 2][r] = (USH)f2b(v.z);
        Ts[tc4 + 3][r] = (USH)f2b(v.w);
    }
    __syncthreads();
    #pragma unroll
    for (int ph = 0; ph < 4; ++ph) {
        const int cc = ph * 16 + tr;
        ushort4 o;
        o.x = Ts[cc][tc4 + 0]; o.y = Ts[cc][tc4 + 1];
        o.z = Ts[cc][tc4 + 2]; o.w = Ts[cc][tc4 + 3];
        *(ushort4*)&out[(size_t)(c0 + cc) * R + r0 + tc4] = o;
    }
}

// ---------------------------------------------------------------------------
// bf16 MFMA GEMM, m97 structure: C = A[M,K] @ Bt[N,K]^T + bias.
// 128x128 tile, BK=32, 4 waves x (64x64), global_load_lds staging with
// source-side XOR swizzle (chunk kq ^= (row>>1)&3), swizzled ds_read_b128.
// QKV=1: scatter n<1024 -> q fp32, n<2048 -> k bf16, else v bf16, all in
// [B*H][S][64] layout.
// ---------------------------------------------------------------------------
template<int QKV>
__global__ __launch_bounds__(256)
void mfma_gemm_kernel(const USH* __restrict__ A, const USH* __restrict__ Bt,
                      const float* __restrict__ bias,
                      float* __restrict__ Cq, USH* __restrict__ Ck,
                      USH* __restrict__ Cv, int M, int N, int K) {
    __shared__ __align__(16) USH As[128 * 32];
    __shared__ __align__(16) USH Bs[128 * 32];
    const int t = threadIdx.x;
    const int w = t >> 6, lane = t & 63, g = lane >> 4, c = lane & 15;
    const int wm = w >> 1, wn = w & 1;
    const int bm0 = blockIdx.y * 128, bn0 = blockIdx.x * 128;

    // staging: chunk f covers (row=f>>2, kq=f&3); source kq XOR'd by (row>>1)&3
    const int sk = ((t & 3) ^ ((t >> 3) & 3)) * 8;
    const USH* pa0 = A + (size_t)(bm0 + (t >> 2)) * K + sk;
    const USH* pa1 = pa0 + (size_t)64 * K;
    const USH* pb0 = Bt + (size_t)(bn0 + (t >> 2)) * K + sk;
    const USH* pb1 = pb0 + (size_t)64 * K;
    USH* ldsA0 = &As[(t & ~63) * 8];
    USH* ldsA1 = ldsA0 + 2048;
    USH* ldsB0 = &Bs[(t & ~63) * 8];
    USH* ldsB1 = ldsB0 + 2048;

    // fragment read byte offsets (swizzled)
    unsigned aoff[4], boff[4];
    #pragma unroll
    for (int i = 0; i < 4; ++i) {
        const int r = wm * 64 + i * 16 + c;
        aoff[i] = ((unsigned)(r * 64 + g * 16)) ^ ((((unsigned)r >> 1) & 3) << 4);
        const int n = wn * 64 + i * 16 + c;
        boff[i] = ((unsigned)(n * 64 + g * 16)) ^ ((((unsigned)n >> 1) & 3) << 4);
    }

    f32x4 acc[4][4];
    #pragma unroll
    for (int i = 0; i < 4; ++i)
        #pragma unroll
        for (int j = 0; j < 4; ++j) acc[i][j] = (f32x4)0.f;

    for (int k0 = 0; k0 < K; k0 += 32) {
        gload16(pa0 + k0, ldsA0);
        gload16(pa1 + k0, ldsA1);
        gload16(pb0 + k0, ldsB0);
        gload16(pb1 + k0, ldsB1);
        __syncthreads();

        bf16x8 af[4], bfr[4];
        #pragma unroll
        for (int i = 0; i < 4; ++i) af[i] = *(const bf16x8*)((const char*)As + aoff[i]);
        #pragma unroll
        for (int j = 0; j < 4; ++j) bfr[j] = *(const bf16x8*)((const char*)Bs + boff[j]);
        #pragma unroll
        for (int i = 0; i < 4; ++i)
            #pragma unroll
            for (int j = 0; j < 4; ++j)
                acc[i][j] = __builtin_amdgcn_mfma_f32_16x16x32_bf16(
                    af[i], bfr[j], acc[i][j], 0, 0, 0);
        __syncthreads();
    }

    #pragma unroll
    for (int i = 0; i < 4; ++i) {
        #pragma unroll
        for (int reg = 0; reg < 4; ++reg) {
            const int m = bm0 + wm * 64 + i * 16 + g * 4 + reg;
            #pragma unroll
            for (int j = 0; j < 4; ++j) {
                const int n = bn0 + wn * 64 + j * 16 + c;
                const float v = acc[i][j][reg] + bias[n];
                if (QKV) {
                    const int which = n >> 10;
                    const int h = (n & 1023) >> 6, d = n & 63;
                    const int b = m >> 10, s = m & 1023;
                    const size_t idx = (((size_t)(b * NH + h)) * S_LEN + s) * DK + d;
                    if (which == 0)      Cq[idx] = v;
                    else if (which == 1) Ck[idx] = (USH)f2b(v);
                    else                 Cv[idx] = (USH)f2b(v);
                } else {
                    Cq[(size_t)m * N + n] = v;
                }
            }
        }
    }
}

// ---------------------------------------------------------------------------
// MFMA flash attention (validated R2) — k/v inputs now bf16, output bf16.
// ---------------------------------------------------------------------------
__global__ __launch_bounds__(256, 4)
void attn_mfma_kernel(const float* __restrict__ qb,
                      const USH* __restrict__ kbuf,
                      const USH* __restrict__ vbuf,
                      const float* __restrict__ lut_k,
                      const float* __restrict__ lut_v,
                      USH* __restrict__ ao) {
    const int blk = blockIdx.x;
    const int ib = blk & 15;
    const int bh = blk >> 4;
    const int b = bh >> 4, h = bh & 15;
    const int i0 = ib * 64;
    const int t = threadIdx.x;
    const int w = t >> 6;
    const int lane = t & 63;
    const int g = lane >> 4;
    const int c = lane & 15;

    __shared__ __align__(16) char smem[37376];
    char* ktb = smem;
    char* vtb = smem + 8192;
    char* pb  = smem + 16384;
    float* qrel  = (float*)(smem + 24576);
    float* lvf   = (float*)(smem + 24576 + 4352);
    float* tapss = (float*)(smem + 24576 + 8704);
    float* qf  = (float*)smem;
    float* lkf = (float*)pb;

    const float* qp = qb + (size_t)bh * (S_LEN * DK);
    const USH* kp = kbuf + (size_t)bh * (S_LEN * DK);
    const USH* vp = vbuf + (size_t)bh * (S_LEN * DK);

    for (int f = t; f < 1024; f += 256) {
        const int row = f >> 4, c4 = (f & 15) * 4;
        *(float4*)&qf[row * 64 + c4] =
            *(const float4*)&qp[(size_t)(i0 + row) * DK + c4];
    }
    for (int e = t; e < 17 * 64; e += 256) {
        lkf[e] = lut_k[e];
        lvf[e] = lut_v[e];
    }
    __syncthreads();

    {
        const int r = t & 63;
        for (int tap = t >> 6; tap < 17; tap += 4) {
            float s = 0.f;
            for (int dd = 0; dd < 64; ++dd) {
                const int d = (dd + r) & 63;
                s += qf[r * 64 + d] * lkf[tap * 64 + d];
            }
            qrel[r * 17 + tap] = s;
        }
    }

    bf16x8 qa[2];
    {
        const int row = w * 16 + c;
        #pragma unroll
        for (int kh = 0; kh < 2; ++kh) {
            f32x4 lo = *(f32x4*)&qf[row * 64 + kh * 32 + g * 8];
            f32x4 hi = *(f32x4*)&qf[row * 64 + kh * 32 + g * 8 + 4];
            bf16x8 v;
            v[0] = f2b(lo[0]); v[1] = f2b(lo[1]); v[2] = f2b(lo[2]); v[3] = f2b(lo[3]);
            v[4] = f2b(hi[0]); v[5] = f2b(hi[1]); v[6] = f2b(hi[2]); v[7] = f2b(hi[3]);
            qa[kh] = v;
        }
    }
    __syncthreads();

    f32x4 acc[4];
    #pragma unroll
    for (int dt = 0; dt < 4; ++dt) acc[dt] = (f32x4)0.f;
    float m_r[4], l_r[4];
    #pragma unroll
    for (int r = 0; r < 4; ++r) { m_r[r] = -INFINITY; l_r[r] = 0.f; }

    const int NT = ib + 1;
    for (int tile = 0; tile < NT; ++tile) {
        const int j0 = tile << 6;

        #pragma unroll
        for (int it = 0; it < 4; ++it) {
            const int f = it * 256 + t;
            const int row = f >> 4, c4 = (f & 15) * 4;
            const ushort4 kb4 = *(const ushort4*)&kp[(size_t)(j0 + row) * DK + c4];
            unsigned kbyte = ((unsigned)row << 7) + ((unsigned)c4 << 1);
            kbyte ^= (unsigned)(row & 7) << 4;
            *(ushort4*)(ktb + kbyte) = kb4;

            const ushort4 vv4 = *(const ushort4*)&vp[(size_t)(j0 + row) * DK + c4];
            const USH vsc[4] = { vv4.x, vv4.y, vv4.z, vv4.w };
            #pragma unroll
            for (int ww = 0; ww < 4; ++ww) {
                const int d = c4 + ww;
                unsigned vbyte = ((unsigned)d << 7) + ((unsigned)row << 1);
                vbyte ^= (unsigned)(((d >> 2) ^ d) & 7) << 4;
                *(USH*)(vtb + vbyte) = vsc[ww];
            }
        }
        __syncthreads();

        float p[4][4];
        #pragma unroll
        for (int sub = 0; sub < 4; ++sub) {
            f32x4 s = (f32x4)0.f;
            const int krow = sub * 16 + c;
            #pragma unroll
            for (int kh = 0; kh < 2; ++kh) {
                unsigned byte = ((unsigned)krow << 7) + ((unsigned)kh << 6) + ((unsigned)g << 4);
                byte ^= (unsigned)(krow & 7) << 4;
                bf16x8 kb = *(bf16x8*)(ktb + byte);
                s = __builtin_amdgcn_mfma_f32_16x16x32_bf16(qa[kh], kb, s, 0, 0, 0);
            }
            const int dbase = (tile - ib) * 64 + (sub * 16 + c) - (w * 16 + g * 4);
            #pragma unroll
            for (int r = 0; r < 4; ++r) {
                const int dj = dbase - r;
                int t17 = dj + 16;
                t17 = t17 < 0 ? 0 : (t17 > 16 ? 16 : t17);
                const int il = w * 16 + g * 4 + r;
                float sc = (s[r] + qrel[il * 17 + t17]) * 0.125f;
                if (tile == ib && dj > 0) sc = -INFINITY;
                p[sub][r] = sc;
            }
        }

        if (tile >= ib - 1) {
            #pragma unroll
            for (int sub = 0; sub < 4; ++sub) {
                const int dbase = (tile - ib) * 64 + (sub * 16 + c) - (w * 16 + g * 4);
                #pragma unroll
                for (int r = 0; r < 4; ++r) {
                    const int dj = dbase - r;
                    if (dj >= -15 && dj <= 0) {
                        const int il = w * 16 + g * 4 + r;
                        tapss[il * 16 + dj + 15] = p[sub][r];
                    }
                }
            }
        }

        #pragma unroll
        for (int r = 0; r < 4; ++r) {
            float mx = fmaxf(fmaxf(p[0][r], p[1][r]), fmaxf(p[2][r], p[3][r]));
            #pragma unroll
            for (int msk = 1; msk < 16; msk <<= 1)
                mx = fmaxf(mx, __shfl_xor(mx, msk));
            const float mn = fmaxf(m_r[r], mx);
            const float scale = __expf(m_r[r] - mn);
            m_r[r] = mn;
            float sum = 0.f;
            #pragma unroll
            for (int sub = 0; sub < 4; ++sub) {
                const float pe = __expf(p[sub][r] - mn);
                p[sub][r] = pe;
                sum += pe;
            }
            #pragma unroll
            for (int msk = 1; msk < 16; msk <<= 1)
                sum += __shfl_xor(sum, msk);
            l_r[r] = l_r[r] * scale + sum;
            #pragma unroll
            for (int dt = 0; dt < 4; ++dt) acc[dt][r] *= scale;
        }

        char* pw = pb + w * 2048;
        #pragma unroll
        for (int sub = 0; sub < 4; ++sub)
            #pragma unroll
            for (int r = 0; r < 4; ++r) {
                const int row = g * 4 + r;
                unsigned byte = ((unsigned)row << 7) + (((unsigned)(sub * 16 + c)) << 1);
                byte ^= (unsigned)(row & 7) << 4;
                *(short*)(pw + byte) = f2b(p[sub][r]);
            }

        bf16x8 pa[2];
        #pragma unroll
        for (int jh = 0; jh < 2; ++jh) {
            unsigned byte = ((unsigned)c << 7) + ((unsigned)jh << 6) + ((unsigned)g << 4);
            byte ^= (unsigned)(c & 7) << 4;
            pa[jh] = *(bf16x8*)(pw + byte);
        }
        #pragma unroll
        for (int dt = 0; dt < 4; ++dt) {
            const int d = dt * 16 + c;
            #pragma unroll
            for (int jh = 0; jh < 2; ++jh) {
                unsigned byte = ((unsigned)d << 7) + ((unsigned)jh << 6) + ((unsigned)g << 4);
                byte ^= (unsigned)(((d >> 2) ^ d) & 7) << 4;
                bf16x8 vb = *(bf16x8*)(vtb + byte);
                acc[dt] = __builtin_amdgcn_mfma_f32_16x16x32_bf16(pa[jh], vb, acc[dt], 0, 0, 0);
            }
        }
        __syncthreads();
    }

    const int rbase = w * 16 + g * 4;
    #pragma unroll
    for (int r = 0; r < 4; ++r) {
        const int il = rbase + r;
        const float mr = m_r[r];
        float c0 = l_r[r];
        float tp[16];
        #pragma unroll
        for (int tap = 0; tap < 16; ++tap) {
            const int jg = i0 + il + tap - 15;
            float pv = 0.f;
            if (jg >= 0) pv = __expf(tapss[il * 16 + tap] - mr);
            tp[tap] = pv;
            c0 -= pv;
        }
        const float invl = 1.f / l_r[r];
        #pragma unroll
        for (int dt = 0; dt < 4; ++dt) {
            const int d = dt * 16 + c;
            float o = acc[dt][r] + c0 * lvf[d];
            #pragma unroll
            for (int tap = 0; tap < 16; ++tap)
                o += tp[tap] * lvf[(tap + 1) * 64 + d];
            o *= invl;
            ao[((size_t)b * S_LEN + (i0 + il)) * D_MODEL + h * DK + d] = (USH)f2b(o);
        }
    }
}

// ---------------------------------------------------------------------------
extern "C" void kernel_launch(void* const* d_in, const int* in_sizes, int n_in,
                              void* d_out, int out_size, void* d_ws, size_t ws_size,
                              hipStream_t stream) {
    const float* x      = (const float*)d_in[0];
    const float* W_attn = (const float*)d_in[1];
    const float* b_attn = (const float*)d_in[2];
    const float* W_proj = (const float*)d_in[3];
    const float* b_proj = (const float*)d_in[4];
    const float* lut_k  = (const float*)d_in[5];
    const float* lut_v  = (const float*)d_in[6];
    float* out = (float*)d_out;

    // workspace layout
    float* q    = (float*)d_ws;                 // 8388608 f32
    USH* kb     = (USH*)(q + HSZ);              // 8388608 bf16
    USH* vb     = kb + HSZ;                     // 8388608
    USH* aob    = vb + HSZ;                     // 8388608
    USH* xb     = aob + HSZ;                    // 8388608
    USH* watt   = xb + HSZ;                     // 3145728
    USH* wproj  = watt + 3145728;               // 1048576

    // 0) conversions
    conv_bf16_kernel<<<HSZ / (256 * 8), 256, 0, stream>>>(x, xb);
    transp_bf16_kernel<<<dim3(3072 / 64, 1024 / 64), 256, 0, stream>>>(
        W_attn, watt, 1024, 3072);
    transp_bf16_kernel<<<dim3(1024 / 64, 1024 / 64), 256, 0, stream>>>(
        W_proj, wproj, 1024, 1024);

    // 1) QKV projection (bf16 MFMA): [8192,1024]@[1024,3072]+bias
    mfma_gemm_kernel<1><<<dim3(3072 / 128, 8192 / 128), 256, 0, stream>>>(
        xb, watt, b_attn, q, kb, vb, 8192, 3072, 1024);

    // 2) attention
    attn_mfma_kernel<<<2048, 256, 0, stream>>>(q, kb, vb, lut_k, lut_v, aob);

    // 3) output projection (bf16 MFMA): [8192,1024]@[1024,1024]+bias
    mfma_gemm_kernel<0><<<dim3(1024 / 128, 8192 / 128), 256, 0, stream>>>(
        aob, wproj, b_proj, out, nullptr, nullptr, 8192, 1024, 1024);
}

// Round 5
// 274.749 us; speedup vs baseline: 10.4895x; 1.5848x over previous
//
#include <hip/hip_runtime.h>
#include <hip/hip_bf16.h>
#include <math.h>

#define NH 16
#define S_LEN 1024
#define DK 64
#define D_MODEL 1024
#define HSZ 8388608          // B*NH*S*DK elements per q/k/v buffer

typedef __attribute__((ext_vector_type(8))) short bf16x8;
typedef __attribute__((ext_vector_type(4))) float f32x4;
typedef unsigned short USH;

__device__ __forceinline__ short f2b(float x) {
    union { __hip_bfloat16 h; short s; } u;
    u.h = __float2bfloat16(x);
    return u.s;
}
__device__ __forceinline__ float b2f(USH u) {
    union { unsigned i; float f; } x;
    x.i = (unsigned)u << 16;
    return x.f;
}

__device__ __forceinline__ void gload16(const void* src, void* lds) {
    __builtin_amdgcn_global_load_lds(
        (const __attribute__((address_space(1))) void*)src,
        (__attribute__((address_space(3))) void*)lds,
        16, 0, 0);
}

// ---------------------------------------------------------------------------
// fp32 -> bf16 conversion (exact-grid, 8 elems/thread)
// ---------------------------------------------------------------------------
__global__ __launch_bounds__(256)
void conv_bf16_kernel(const float* __restrict__ in, USH* __restrict__ out) {
    const int i = (blockIdx.x * 256 + threadIdx.x) * 8;
    const float4 a = *(const float4*)&in[i];
    const float4 b = *(const float4*)&in[i + 4];
    ushort4 o0, o1;
    o0.x = (USH)f2b(a.x); o0.y = (USH)f2b(a.y); o0.z = (USH)f2b(a.z); o0.w = (USH)f2b(a.w);
    o1.x = (USH)f2b(b.x); o1.y = (USH)f2b(b.y); o1.z = (USH)f2b(b.z); o1.w = (USH)f2b(b.w);
    *(ushort4*)&out[i] = o0;
    *(ushort4*)&out[i + 4] = o1;
}

// ---------------------------------------------------------------------------
// Transpose + convert: in [R][C] fp32 -> out [C][R] bf16. 64x64 tiles.
// ---------------------------------------------------------------------------
__global__ __launch_bounds__(256)
void transp_bf16_kernel(const float* __restrict__ in, USH* __restrict__ out,
                        int R, int C) {
    __shared__ USH Ts[64][65];
    const int r0 = blockIdx.y * 64, c0 = blockIdx.x * 64;
    const int tr = threadIdx.x >> 4;
    const int tc4 = (threadIdx.x & 15) * 4;
    #pragma unroll
    for (int ph = 0; ph < 4; ++ph) {
        const int r = ph * 16 + tr;
        const float4 v = *(const float4*)&in[(size_t)(r0 + r) * C + c0 + tc4];
        Ts[tc4 + 0][r] = (USH)f2b(v.x);
        Ts[tc4 + 1][r] = (USH)f2b(v.y);
        Ts[tc4 + 2][r] = (USH)f2b(v.z);
        Ts[tc4 + 3][r] = (USH)f2b(v.w);
    }
    __syncthreads();
    #pragma unroll
    for (int ph = 0; ph < 4; ++ph) {
        const int cc = ph * 16 + tr;
        ushort4 o;
        o.x = Ts[cc][tc4 + 0]; o.y = Ts[cc][tc4 + 1];
        o.z = Ts[cc][tc4 + 2]; o.w = Ts[cc][tc4 + 3];
        *(ushort4*)&out[(size_t)(c0 + cc) * R + r0 + tc4] = o;
    }
}

// ---------------------------------------------------------------------------
// Per-head V transpose (bf16): in [bh][s][64] -> out [bh][d=64][s=1024]
// ---------------------------------------------------------------------------
__global__ __launch_bounds__(256)
void vtransp_kernel(const USH* __restrict__ in, USH* __restrict__ out) {
    __shared__ USH T[64][72];
    const int bh = blockIdx.x >> 4;
    const int s0 = (blockIdx.x & 15) * 64;
    const int r = threadIdx.x >> 4;
    const int c4 = (threadIdx.x & 15) * 4;
    #pragma unroll
    for (int ph = 0; ph < 4; ++ph) {
        const int row = ph * 16 + r;   // s offset
        const ushort4 v = *(const ushort4*)
            &in[((size_t)bh * S_LEN + s0 + row) * DK + c4];
        T[row][c4 + 0] = v.x; T[row][c4 + 1] = v.y;
        T[row][c4 + 2] = v.z; T[row][c4 + 3] = v.w;
    }
    __syncthreads();
    #pragma unroll
    for (int ph = 0; ph < 4; ++ph) {
        const int d = ph * 16 + r;
        ushort4 o;
        o.x = T[c4 + 0][d]; o.y = T[c4 + 1][d];
        o.z = T[c4 + 2][d]; o.w = T[c4 + 3][d];
        *(ushort4*)&out[(size_t)bh * (S_LEN * DK) + (size_t)d * S_LEN + s0 + c4] = o;
    }
}

// ---------------------------------------------------------------------------
// bf16 MFMA GEMM (m97 structure) — q/k/v written bf16 when QKV=1.
// ---------------------------------------------------------------------------
template<int QKV>
__global__ __launch_bounds__(256)
void mfma_gemm_kernel(const USH* __restrict__ A, const USH* __restrict__ Bt,
                      const float* __restrict__ bias,
                      float* __restrict__ Cf, USH* __restrict__ Cq,
                      USH* __restrict__ Ck, USH* __restrict__ Cv,
                      int M, int N, int K) {
    __shared__ __align__(16) USH As[128 * 32];
    __shared__ __align__(16) USH Bs[128 * 32];
    const int t = threadIdx.x;
    const int w = t >> 6, lane = t & 63, g = lane >> 4, c = lane & 15;
    const int wm = w >> 1, wn = w & 1;
    const int bm0 = blockIdx.y * 128, bn0 = blockIdx.x * 128;

    const int sk = ((t & 3) ^ ((t >> 3) & 3)) * 8;
    const USH* pa0 = A + (size_t)(bm0 + (t >> 2)) * K + sk;
    const USH* pa1 = pa0 + (size_t)64 * K;
    const USH* pb0 = Bt + (size_t)(bn0 + (t >> 2)) * K + sk;
    const USH* pb1 = pb0 + (size_t)64 * K;
    USH* ldsA0 = &As[(t & ~63) * 8];
    USH* ldsA1 = ldsA0 + 2048;
    USH* ldsB0 = &Bs[(t & ~63) * 8];
    USH* ldsB1 = ldsB0 + 2048;

    unsigned aoff[4], boff[4];
    #pragma unroll
    for (int i = 0; i < 4; ++i) {
        const int r = wm * 64 + i * 16 + c;
        aoff[i] = ((unsigned)(r * 64 + g * 16)) ^ ((((unsigned)r >> 1) & 3) << 4);
        const int n = wn * 64 + i * 16 + c;
        boff[i] = ((unsigned)(n * 64 + g * 16)) ^ ((((unsigned)n >> 1) & 3) << 4);
    }

    f32x4 acc[4][4];
    #pragma unroll
    for (int i = 0; i < 4; ++i)
        #pragma unroll
        for (int j = 0; j < 4; ++j) acc[i][j] = (f32x4)0.f;

    for (int k0 = 0; k0 < K; k0 += 32) {
        gload16(pa0 + k0, ldsA0);
        gload16(pa1 + k0, ldsA1);
        gload16(pb0 + k0, ldsB0);
        gload16(pb1 + k0, ldsB1);
        __syncthreads();

        bf16x8 af[4], bfr[4];
        #pragma unroll
        for (int i = 0; i < 4; ++i) af[i] = *(const bf16x8*)((const char*)As + aoff[i]);
        #pragma unroll
        for (int j = 0; j < 4; ++j) bfr[j] = *(const bf16x8*)((const char*)Bs + boff[j]);
        #pragma unroll
        for (int i = 0; i < 4; ++i)
            #pragma unroll
            for (int j = 0; j < 4; ++j)
                acc[i][j] = __builtin_amdgcn_mfma_f32_16x16x32_bf16(
                    af[i], bfr[j], acc[i][j], 0, 0, 0);
        __syncthreads();
    }

    #pragma unroll
    for (int i = 0; i < 4; ++i) {
        #pragma unroll
        for (int reg = 0; reg < 4; ++reg) {
            const int m = bm0 + wm * 64 + i * 16 + g * 4 + reg;
            #pragma unroll
            for (int j = 0; j < 4; ++j) {
                const int n = bn0 + wn * 64 + j * 16 + c;
                const float v = acc[i][j][reg] + bias[n];
                if (QKV) {
                    const int which = n >> 10;
                    const int h = (n & 1023) >> 6, d = n & 63;
                    const int b = m >> 10, s = m & 1023;
                    const size_t idx = (((size_t)(b * NH + h)) * S_LEN + s) * DK + d;
                    if (which == 0)      Cq[idx] = (USH)f2b(v);
                    else if (which == 1) Ck[idx] = (USH)f2b(v);
                    else                 Cv[idx] = (USH)f2b(v);
                } else {
                    Cf[(size_t)m * N + n] = v;
                }
            }
        }
    }
}

// ---------------------------------------------------------------------------
// MFMA flash attention, double-buffered async staging.
// Block = (b,h, 64 q-rows); 4 waves x 16 rows; KVBLK=64.
// LDS map (53760 B):
//   0      ktb0   8KB     (phase0: ---)
//   8192   ktb1   8KB     (phase0: q bf16, swizzled)
//   16384  vtb0   8KB
//   24576  vtb1   8KB
//   32768  pb     8KB     (phase0: lkf fp32 4352B)
//   40960  qrel   4352B
//   45312  lvf    4352B
//   49664  tapss  4096B
// Swizzle involution everywhere: 16B-chunk ^= (row&7), applied to the
// global SOURCE for global_load_lds (LDS linear) and to the ds_read side.
// ---------------------------------------------------------------------------
__global__ __launch_bounds__(256, 3)
void attn_mfma_kernel(const USH* __restrict__ qb,
                      const USH* __restrict__ kbuf,
                      const USH* __restrict__ vtg,
                      const float* __restrict__ lut_k,
                      const float* __restrict__ lut_v,
                      USH* __restrict__ ao) {
    const int bid = blockIdx.x;
    const int logical = (bid & 7) * 256 + (bid >> 3);   // XCD-contiguous bh
    const int ib = logical & 15;
    const int bh = logical >> 4;
    const int b = bh >> 4, h = bh & 15;
    const int i0 = ib * 64;
    const int t = threadIdx.x;
    const int w = t >> 6;
    const int lane = t & 63;
    const int g = lane >> 4;
    const int c = lane & 15;

    __shared__ __align__(16) char smem[53760];
    char* qsb = smem + 8192;                 // aliases ktb1 (phase 0 only)
    char* pb  = smem + 32768;
    float* qrel  = (float*)(smem + 40960);
    float* lkf   = (float*)(smem + 32768);   // aliases pb (phase 0 only)
    float* lvf   = (float*)(smem + 45312);
    float* tapss = (float*)(smem + 49664);

    const USH* qp  = qb   + (size_t)bh * (S_LEN * DK);
    const USH* kp  = kbuf + (size_t)bh * (S_LEN * DK);
    const USH* vtp = vtg  + (size_t)bh * (S_LEN * DK);  // [d=64][s=1024]

    // async stage of one 64x64 K tile + V^T tile into (koff,voff)
    auto stage = [&](int j0, int koff, int voff) {
        #pragma unroll
        for (int qq = 0; qq < 2; ++qq) {
            const int o = (w * 2 + qq) * 1024 + lane * 16;
            const int row = o >> 7;
            const int chunk = (o >> 4) & 7;
            const int sc = (chunk ^ (row & 7)) * 8;
            gload16(kp + (size_t)(j0 + row) * DK + sc,
                    smem + koff + (w * 2 + qq) * 1024);
            gload16(vtp + (size_t)row * S_LEN + j0 + sc,
                    smem + voff + (w * 2 + qq) * 1024);
        }
    };

    // ---- phase 0: issue tile-0 loads; stage q (bf16, swizzled) + LUTs ----
    stage(0, 0, 16384);
    for (int f = t; f < 1024; f += 256) {
        const int row = f >> 4, c4 = (f & 15) * 4;
        unsigned byte = ((unsigned)(row * 128 + c4 * 2)) ^ (((unsigned)row & 7) << 4);
        *(ushort4*)(qsb + byte) = *(const ushort4*)&qp[(size_t)(i0 + row) * DK + c4];
    }
    for (int e = t; e < 17 * 64; e += 256) {
        lkf[e] = lut_k[e];
        lvf[e] = lut_v[e];
    }
    __syncthreads();   // drains tile-0 gloads too

    // qrel[r][tap] = q_row(i0+r) . lut_k[tap]
    {
        const int r = t & 63;
        for (int tap = t >> 6; tap < 17; tap += 4) {
            float s = 0.f;
            for (int dd = 0; dd < 64; ++dd) {
                const int d = (dd + r) & 63;
                unsigned byte = ((unsigned)(r * 128 + d * 2)) ^ (((unsigned)r & 7) << 4);
                s += b2f(*(const USH*)(qsb + byte)) * lkf[tap * 64 + d];
            }
            qrel[r * 17 + tap] = s;
        }
    }

    // Q fragments straight from swizzled bf16 LDS
    bf16x8 qa[2];
    {
        const int row = w * 16 + c;
        #pragma unroll
        for (int kh = 0; kh < 2; ++kh) {
            unsigned byte = ((unsigned)(row * 128 + kh * 64 + g * 16))
                          ^ (((unsigned)row & 7) << 4);
            qa[kh] = *(const bf16x8*)(qsb + byte);
        }
    }
    __syncthreads();   // qsb/lkf dead; qrel/lvf live

    f32x4 acc[4];
    #pragma unroll
    for (int dt = 0; dt < 4; ++dt) acc[dt] = (f32x4)0.f;
    float m_r[4], l_r[4];
    #pragma unroll
    for (int r = 0; r < 4; ++r) { m_r[r] = -INFINITY; l_r[r] = 0.f; }

    const int NT = ib + 1;
    for (int tile = 0; tile < NT; ++tile) {
        const int cur = tile & 1;
        if (tile + 1 < NT)
            stage((tile + 1) << 6, cur ? 0 : 8192, cur ? 16384 : 24576);
        const char* ktb = smem + (cur ? 8192 : 0);
        const char* vtb = smem + (cur ? 24576 : 16384);

        // ---- QK^T + score fixup ----
        float p[4][4];
        #pragma unroll
        for (int sub = 0; sub < 4; ++sub) {
            f32x4 s = (f32x4)0.f;
            const int krow = sub * 16 + c;
            #pragma unroll
            for (int kh = 0; kh < 2; ++kh) {
                unsigned byte = ((unsigned)krow << 7) + ((unsigned)kh << 6) + ((unsigned)g << 4);
                byte ^= (unsigned)(krow & 7) << 4;
                bf16x8 kb = *(const bf16x8*)(ktb + byte);
                s = __builtin_amdgcn_mfma_f32_16x16x32_bf16(qa[kh], kb, s, 0, 0, 0);
            }
            const int dbase = (tile - ib) * 64 + (sub * 16 + c) - (w * 16 + g * 4);
            #pragma unroll
            for (int r = 0; r < 4; ++r) {
                const int dj = dbase - r;
                int t17 = dj + 16;
                t17 = t17 < 0 ? 0 : (t17 > 16 ? 16 : t17);
                const int il = w * 16 + g * 4 + r;
                float sc = (s[r] + qrel[il * 17 + t17]) * 0.125f;
                if (tile == ib && dj > 0) sc = -INFINITY;
                p[sub][r] = sc;
            }
        }

        // ---- capture tap scores (dj in [-15,0]) ----
        if (tile >= ib - 1) {
            #pragma unroll
            for (int sub = 0; sub < 4; ++sub) {
                const int dbase = (tile - ib) * 64 + (sub * 16 + c) - (w * 16 + g * 4);
                #pragma unroll
                for (int r = 0; r < 4; ++r) {
                    const int dj = dbase - r;
                    if (dj >= -15 && dj <= 0) {
                        const int il = w * 16 + g * 4 + r;
                        tapss[il * 16 + dj + 15] = p[sub][r];
                    }
                }
            }
        }

        // ---- online softmax ----
        #pragma unroll
        for (int r = 0; r < 4; ++r) {
            float mx = fmaxf(fmaxf(p[0][r], p[1][r]), fmaxf(p[2][r], p[3][r]));
            #pragma unroll
            for (int msk = 1; msk < 16; msk <<= 1)
                mx = fmaxf(mx, __shfl_xor(mx, msk));
            const float mn = fmaxf(m_r[r], mx);
            const float scale = __expf(m_r[r] - mn);
            m_r[r] = mn;
            float sum = 0.f;
            #pragma unroll
            for (int sub = 0; sub < 4; ++sub) {
                const float pe = __expf(p[sub][r] - mn);
                p[sub][r] = pe;
                sum += pe;
            }
            #pragma unroll
            for (int msk = 1; msk < 16; msk <<= 1)
                sum += __shfl_xor(sum, msk);
            l_r[r] = l_r[r] * scale + sum;
            #pragma unroll
            for (int dt = 0; dt < 4; ++dt) acc[dt][r] *= scale;
        }

        // ---- P -> per-wave LDS (bf16, swizzled) ----
        char* pw = pb + w * 2048;
        #pragma unroll
        for (int sub = 0; sub < 4; ++sub)
            #pragma unroll
            for (int r = 0; r < 4; ++r) {
                const int row = g * 4 + r;
                unsigned byte = ((unsigned)row << 7) + (((unsigned)(sub * 16 + c)) << 1);
                byte ^= (unsigned)(row & 7) << 4;
                *(short*)(pw + byte) = f2b(p[sub][r]);
            }

        // ---- PV ----
        bf16x8 pa[2];
        #pragma unroll
        for (int jh = 0; jh < 2; ++jh) {
            unsigned byte = ((unsigned)c << 7) + ((unsigned)jh << 6) + ((unsigned)g << 4);
            byte ^= (unsigned)(c & 7) << 4;
            pa[jh] = *(const bf16x8*)(pw + byte);
        }
        #pragma unroll
        for (int dt = 0; dt < 4; ++dt) {
            const int d = dt * 16 + c;
            #pragma unroll
            for (int jh = 0; jh < 2; ++jh) {
                unsigned byte = ((unsigned)d << 7) + ((unsigned)jh << 6) + ((unsigned)g << 4);
                byte ^= (unsigned)(d & 7) << 4;
                bf16x8 vb = *(const bf16x8*)(vtb + byte);
                acc[dt] = __builtin_amdgcn_mfma_f32_16x16x32_bf16(pa[jh], vb, acc[dt], 0, 0, 0);
            }
        }
        __syncthreads();
    }

    // ---- epilogue: taps + bin-0 residual + normalize + write ----
    const int rbase = w * 16 + g * 4;
    #pragma unroll
    for (int r = 0; r < 4; ++r) {
        const int il = rbase + r;
        const float mr = m_r[r];
        float c0 = l_r[r];
        float tp[16];
        #pragma unroll
        for (int tap = 0; tap < 16; ++tap) {
            const int jg = i0 + il + tap - 15;
            float pv = 0.f;
            if (jg >= 0) pv = __expf(tapss[il * 16 + tap] - mr);
            tp[tap] = pv;
            c0 -= pv;
        }
        const float invl = 1.f / l_r[r];
        #pragma unroll
        for (int dt = 0; dt < 4; ++dt) {
            const int d = dt * 16 + c;
            float o = acc[dt][r] + c0 * lvf[d];
            #pragma unroll
            for (int tap = 0; tap < 16; ++tap)
                o += tp[tap] * lvf[(tap + 1) * 64 + d];
            o *= invl;
            ao[((size_t)b * S_LEN + (i0 + il)) * D_MODEL + h * DK + d] = (USH)f2b(o);
        }
    }
}

// ---------------------------------------------------------------------------
extern "C" void kernel_launch(void* const* d_in, const int* in_sizes, int n_in,
                              void* d_out, int out_size, void* d_ws, size_t ws_size,
                              hipStream_t stream) {
    const float* x      = (const float*)d_in[0];
    const float* W_attn = (const float*)d_in[1];
    const float* b_attn = (const float*)d_in[2];
    const float* W_proj = (const float*)d_in[3];
    const float* b_proj = (const float*)d_in[4];
    const float* lut_k  = (const float*)d_in[5];
    const float* lut_v  = (const float*)d_in[6];
    float* out = (float*)d_out;

    // workspace layout (all USH)
    USH* qb    = (USH*)d_ws;            // 8M
    USH* kb    = qb + HSZ;              // 8M
    USH* vb    = kb + HSZ;              // 8M (row-major V)
    USH* vtg   = vb + HSZ;              // 8M (per-head transposed V)
    USH* aob   = vtg + HSZ;             // 8M
    USH* xb    = aob + HSZ;             // 8M
    USH* watt  = xb + HSZ;              // 3M
    USH* wproj = watt + 3145728;        // 1M

    // 0) conversions
    conv_bf16_kernel<<<HSZ / (256 * 8), 256, 0, stream>>>(x, xb);
    transp_bf16_kernel<<<dim3(3072 / 64, 1024 / 64), 256, 0, stream>>>(
        W_attn, watt, 1024, 3072);
    transp_bf16_kernel<<<dim3(1024 / 64, 1024 / 64), 256, 0, stream>>>(
        W_proj, wproj, 1024, 1024);

    // 1) QKV projection (bf16 MFMA)
    mfma_gemm_kernel<1><<<dim3(3072 / 128, 8192 / 128), 256, 0, stream>>>(
        xb, watt, b_attn, nullptr, qb, kb, vb, 8192, 3072, 1024);

    // 1b) per-head V transpose
    vtransp_kernel<<<2048, 256, 0, stream>>>(vb, vtg);

    // 2) attention
    attn_mfma_kernel<<<2048, 256, 0, stream>>>(qb, kb, vtg, lut_k, lut_v, aob);

    // 3) output projection (bf16 MFMA)
    mfma_gemm_kernel<0><<<dim3(1024 / 128, 8192 / 128), 256, 0, stream>>>(
        aob, wproj, b_proj, out, nullptr, nullptr, nullptr, 8192, 1024, 1024);
}

// Round 6
// 245.199 us; speedup vs baseline: 11.7537x; 1.1205x over previous
//
#include <hip/hip_runtime.h>
#include <hip/hip_bf16.h>
#include <math.h>

#define NH 16
#define S_LEN 1024
#define DK 64
#define D_MODEL 1024
#define HSZ 8388608          // B*NH*S*DK elements per q/k/v buffer

typedef __attribute__((ext_vector_type(8))) short bf16x8;
typedef __attribute__((ext_vector_type(4))) float f32x4;
typedef unsigned short USH;

__device__ __forceinline__ short f2b(float x) {
    union { __hip_bfloat16 h; short s; } u;
    u.h = __float2bfloat16(x);
    return u.s;
}
__device__ __forceinline__ float b2f(USH u) {
    union { unsigned i; float f; } x;
    x.i = (unsigned)u << 16;
    return x.f;
}

__device__ __forceinline__ void gload16(const void* src, void* lds) {
    __builtin_amdgcn_global_load_lds(
        (const __attribute__((address_space(1))) void*)src,
        (__attribute__((address_space(3))) void*)lds,
        16, 0, 0);
}

// ---------------------------------------------------------------------------
// fp32 -> bf16 conversion (exact-grid, 8 elems/thread)
// ---------------------------------------------------------------------------
__global__ __launch_bounds__(256)
void conv_bf16_kernel(const float* __restrict__ in, USH* __restrict__ out) {
    const int i = (blockIdx.x * 256 + threadIdx.x) * 8;
    const float4 a = *(const float4*)&in[i];
    const float4 b = *(const float4*)&in[i + 4];
    ushort4 o0, o1;
    o0.x = (USH)f2b(a.x); o0.y = (USH)f2b(a.y); o0.z = (USH)f2b(a.z); o0.w = (USH)f2b(a.w);
    o1.x = (USH)f2b(b.x); o1.y = (USH)f2b(b.y); o1.z = (USH)f2b(b.z); o1.w = (USH)f2b(b.w);
    *(ushort4*)&out[i] = o0;
    *(ushort4*)&out[i + 4] = o1;
}

// ---------------------------------------------------------------------------
// Transpose + convert: in [R][C] fp32 -> out [C][R] bf16. 64x64 tiles.
// ---------------------------------------------------------------------------
__global__ __launch_bounds__(256)
void transp_bf16_kernel(const float* __restrict__ in, USH* __restrict__ out,
                        int R, int C) {
    __shared__ USH Ts[64][65];
    const int r0 = blockIdx.y * 64, c0 = blockIdx.x * 64;
    const int tr = threadIdx.x >> 4;
    const int tc4 = (threadIdx.x & 15) * 4;
    #pragma unroll
    for (int ph = 0; ph < 4; ++ph) {
        const int r = ph * 16 + tr;
        const float4 v = *(const float4*)&in[(size_t)(r0 + r) * C + c0 + tc4];
        Ts[tc4 + 0][r] = (USH)f2b(v.x);
        Ts[tc4 + 1][r] = (USH)f2b(v.y);
        Ts[tc4 + 2][r] = (USH)f2b(v.z);
        Ts[tc4 + 3][r] = (USH)f2b(v.w);
    }
    __syncthreads();
    #pragma unroll
    for (int ph = 0; ph < 4; ++ph) {
        const int cc = ph * 16 + tr;
        ushort4 o;
        o.x = Ts[cc][tc4 + 0]; o.y = Ts[cc][tc4 + 1];
        o.z = Ts[cc][tc4 + 2]; o.w = Ts[cc][tc4 + 3];
        *(ushort4*)&out[(size_t)(c0 + cc) * R + r0 + tc4] = o;
    }
}

// ---------------------------------------------------------------------------
// Per-head V transpose (bf16): in [bh][s][64] -> out [bh][d=64][s=1024]
// ---------------------------------------------------------------------------
__global__ __launch_bounds__(256)
void vtransp_kernel(const USH* __restrict__ in, USH* __restrict__ out) {
    __shared__ USH T[64][72];
    const int bh = blockIdx.x >> 4;
    const int s0 = (blockIdx.x & 15) * 64;
    const int r = threadIdx.x >> 4;
    const int c4 = (threadIdx.x & 15) * 4;
    #pragma unroll
    for (int ph = 0; ph < 4; ++ph) {
        const int row = ph * 16 + r;   // s offset
        const ushort4 v = *(const ushort4*)
            &in[((size_t)bh * S_LEN + s0 + row) * DK + c4];
        T[row][c4 + 0] = v.x; T[row][c4 + 1] = v.y;
        T[row][c4 + 2] = v.z; T[row][c4 + 3] = v.w;
    }
    __syncthreads();
    #pragma unroll
    for (int ph = 0; ph < 4; ++ph) {
        const int d = ph * 16 + r;
        ushort4 o;
        o.x = T[c4 + 0][d]; o.y = T[c4 + 1][d];
        o.z = T[c4 + 2][d]; o.w = T[c4 + 3][d];
        *(ushort4*)&out[(size_t)bh * (S_LEN * DK) + (size_t)d * S_LEN + s0 + c4] = o;
    }
}

// ---------------------------------------------------------------------------
// bf16 MFMA GEMM (m97 structure) — q/k/v written bf16 when QKV=1.
// ---------------------------------------------------------------------------
template<int QKV>
__global__ __launch_bounds__(256)
void mfma_gemm_kernel(const USH* __restrict__ A, const USH* __restrict__ Bt,
                      const float* __restrict__ bias,
                      float* __restrict__ Cf, USH* __restrict__ Cq,
                      USH* __restrict__ Ck, USH* __restrict__ Cv,
                      int M, int N, int K) {
    __shared__ __align__(16) USH As[128 * 32];
    __shared__ __align__(16) USH Bs[128 * 32];
    const int t = threadIdx.x;
    const int w = t >> 6, lane = t & 63, g = lane >> 4, c = lane & 15;
    const int wm = w >> 1, wn = w & 1;
    const int bm0 = blockIdx.y * 128, bn0 = blockIdx.x * 128;

    const int sk = ((t & 3) ^ ((t >> 3) & 3)) * 8;
    const USH* pa0 = A + (size_t)(bm0 + (t >> 2)) * K + sk;
    const USH* pa1 = pa0 + (size_t)64 * K;
    const USH* pb0 = Bt + (size_t)(bn0 + (t >> 2)) * K + sk;
    const USH* pb1 = pb0 + (size_t)64 * K;
    USH* ldsA0 = &As[(t & ~63) * 8];
    USH* ldsA1 = ldsA0 + 2048;
    USH* ldsB0 = &Bs[(t & ~63) * 8];
    USH* ldsB1 = ldsB0 + 2048;

    unsigned aoff[4], boff[4];
    #pragma unroll
    for (int i = 0; i < 4; ++i) {
        const int r = wm * 64 + i * 16 + c;
        aoff[i] = ((unsigned)(r * 64 + g * 16)) ^ ((((unsigned)r >> 1) & 3) << 4);
        const int n = wn * 64 + i * 16 + c;
        boff[i] = ((unsigned)(n * 64 + g * 16)) ^ ((((unsigned)n >> 1) & 3) << 4);
    }

    f32x4 acc[4][4];
    #pragma unroll
    for (int i = 0; i < 4; ++i)
        #pragma unroll
        for (int j = 0; j < 4; ++j) acc[i][j] = (f32x4)0.f;

    for (int k0 = 0; k0 < K; k0 += 32) {
        gload16(pa0 + k0, ldsA0);
        gload16(pa1 + k0, ldsA1);
        gload16(pb0 + k0, ldsB0);
        gload16(pb1 + k0, ldsB1);
        __syncthreads();

        bf16x8 af[4], bfr[4];
        #pragma unroll
        for (int i = 0; i < 4; ++i) af[i] = *(const bf16x8*)((const char*)As + aoff[i]);
        #pragma unroll
        for (int j = 0; j < 4; ++j) bfr[j] = *(const bf16x8*)((const char*)Bs + boff[j]);
        #pragma unroll
        for (int i = 0; i < 4; ++i)
            #pragma unroll
            for (int j = 0; j < 4; ++j)
                acc[i][j] = __builtin_amdgcn_mfma_f32_16x16x32_bf16(
                    af[i], bfr[j], acc[i][j], 0, 0, 0);
        __syncthreads();
    }

    #pragma unroll
    for (int i = 0; i < 4; ++i) {
        #pragma unroll
        for (int reg = 0; reg < 4; ++reg) {
            const int m = bm0 + wm * 64 + i * 16 + g * 4 + reg;
            #pragma unroll
            for (int j = 0; j < 4; ++j) {
                const int n = bn0 + wn * 64 + j * 16 + c;
                const float v = acc[i][j][reg] + bias[n];
                if (QKV) {
                    const int which = n >> 10;
                    const int h = (n & 1023) >> 6, d = n & 63;
                    const int b = m >> 10, s = m & 1023;
                    const size_t idx = (((size_t)(b * NH + h)) * S_LEN + s) * DK + d;
                    if (which == 0)      Cq[idx] = (USH)f2b(v);
                    else if (which == 1) Ck[idx] = (USH)f2b(v);
                    else                 Cv[idx] = (USH)f2b(v);
                } else {
                    Cf[(size_t)m * N + n] = v;
                }
            }
        }
    }
}

// ---------------------------------------------------------------------------
// MFMA flash attention, double-buffered async staging.
// Block = (b,h, 64 q-rows); 4 waves x 16 rows; KVBLK=64.
// LDS map (49792 B -> 3 blocks/CU):
//   0      ktb0   8KB
//   8192   ktb1   8KB     (phase0: q bf16, swizzled)
//   16384  vtb0   8KB
//   24576  vtb1   8KB
//   32768  pb     8KB     (phase0: lut_k bf16 [32][64] swizzled)
//   40960  qrelb  bf16 [64][20]   2560B
//   43520  lvfb   bf16 [17][64]   2176B
//   45696  tapss  f32  [64][16]   4096B
// Swizzle involution: 16B-chunk ^= (row&7); applied to global SOURCE for
// global_load_lds (LDS linear) and to the ds_read side.
// qrel computed by MFMA (lut_k rows = 17 virtual keys).
// Interior tiles (tile < ib-1): dj <= -65 -> t17 == 0 -> 1-fma fixup.
// ---------------------------------------------------------------------------
__global__ __launch_bounds__(256, 3)
void attn_mfma_kernel(const USH* __restrict__ qb,
                      const USH* __restrict__ kbuf,
                      const USH* __restrict__ vtg,
                      const float* __restrict__ lut_k,
                      const float* __restrict__ lut_v,
                      USH* __restrict__ ao) {
    const int bid = blockIdx.x;
    const int logical = (bid & 7) * 256 + (bid >> 3);   // XCD-contiguous bh
    const int ib = logical & 15;
    const int bh = logical >> 4;
    const int b = bh >> 4, h = bh & 15;
    const int i0 = ib * 64;
    const int t = threadIdx.x;
    const int w = t >> 6;
    const int lane = t & 63;
    const int g = lane >> 4;
    const int c = lane & 15;

    __shared__ __align__(16) char smem[49792];
    char* qsb   = smem + 8192;               // aliases ktb1 (phase 0 only)
    char* pb    = smem + 32768;
    char* lutkb = smem + 32768;              // aliases pb (phase 0 only)
    USH* qrelb  = (USH*)(smem + 40960);      // [64][20] bf16
    USH* lvfb   = (USH*)(smem + 43520);      // [17][64] bf16
    float* tapss = (float*)(smem + 45696);   // [64][16]

    const USH* qp  = qb   + (size_t)bh * (S_LEN * DK);
    const USH* kp  = kbuf + (size_t)bh * (S_LEN * DK);
    const USH* vtp = vtg  + (size_t)bh * (S_LEN * DK);  // [d=64][s=1024]

    // async stage of one 64x64 K tile + V^T tile into (koff,voff)
    auto stage = [&](int j0, int koff, int voff) {
        #pragma unroll
        for (int qq = 0; qq < 2; ++qq) {
            const int o = (w * 2 + qq) * 1024 + lane * 16;
            const int row = o >> 7;
            const int chunk = (o >> 4) & 7;
            const int sc = (chunk ^ (row & 7)) * 8;
            gload16(kp + (size_t)(j0 + row) * DK + sc,
                    smem + koff + (w * 2 + qq) * 1024);
            gload16(vtp + (size_t)row * S_LEN + j0 + sc,
                    smem + voff + (w * 2 + qq) * 1024);
        }
    };

    // ---- phase 0: issue tile-0 loads; stage q (bf16, swizzled) + LUTs ----
    stage(0, 0, 16384);
    for (int f = t; f < 1024; f += 256) {
        const int row = f >> 4, c4 = (f & 15) * 4;
        unsigned byte = ((unsigned)(row * 128 + c4 * 2)) ^ (((unsigned)row & 7) << 4);
        *(ushort4*)(qsb + byte) = *(const ushort4*)&qp[(size_t)(i0 + row) * DK + c4];
    }
    // lut_k -> bf16 LDS [32][64], rows 17..31 zero, swizzled
    for (int e = t; e < 32 * 64; e += 256) {
        const int row = e >> 6, d = e & 63;
        const USH v = (row < 17) ? (USH)f2b(lut_k[row * 64 + d]) : (USH)0;
        unsigned byte = ((unsigned)(row * 128 + d * 2)) ^ (((unsigned)row & 7) << 4);
        *(USH*)(lutkb + byte) = v;
    }
    for (int e = t; e < 17 * 64; e += 256)
        lvfb[e] = (USH)f2b(lut_v[e]);
    __syncthreads();   // drains tile-0 gloads too

    // Q fragments straight from swizzled bf16 LDS
    bf16x8 qa[2];
    {
        const int row = w * 16 + c;
        #pragma unroll
        for (int kh = 0; kh < 2; ++kh) {
            unsigned byte = ((unsigned)(row * 128 + kh * 64 + g * 16))
                          ^ (((unsigned)row & 7) << 4);
            qa[kh] = *(const bf16x8*)(qsb + byte);
        }
    }

    // qrel via MFMA: lut_k rows as 17 virtual keys (2 col sub-tiles)
    {
        f32x4 qr[2];
        qr[0] = (f32x4)0.f; qr[1] = (f32x4)0.f;
        #pragma unroll
        for (int sub2 = 0; sub2 < 2; ++sub2) {
            const int tap = sub2 * 16 + c;
            #pragma unroll
            for (int kh = 0; kh < 2; ++kh) {
                unsigned byte = ((unsigned)(tap * 128 + kh * 64 + g * 16))
                              ^ (((unsigned)tap & 7) << 4);
                bf16x8 lb = *(const bf16x8*)(lutkb + byte);
                qr[sub2] = __builtin_amdgcn_mfma_f32_16x16x32_bf16(
                    qa[kh], lb, qr[sub2], 0, 0, 0);
            }
        }
        #pragma unroll
        for (int sub2 = 0; sub2 < 2; ++sub2) {
            const int tap = sub2 * 16 + c;
            if (tap < 17) {
                #pragma unroll
                for (int r = 0; r < 4; ++r)
                    qrelb[(w * 16 + g * 4 + r) * 20 + tap] = (USH)f2b(qr[sub2][r]);
            }
        }
    }
    __syncthreads();   // qsb/lutkb dead; qrelb ready; pb free for P

    // hoist tap-0 qrel (pre-scaled) for interior tiles
    float qrel0s[4];
    #pragma unroll
    for (int r = 0; r < 4; ++r)
        qrel0s[r] = b2f(qrelb[(w * 16 + g * 4 + r) * 20]) * 0.125f;

    f32x4 acc[4];
    #pragma unroll
    for (int dt = 0; dt < 4; ++dt) acc[dt] = (f32x4)0.f;
    float m_r[4], l_r[4];
    #pragma unroll
    for (int r = 0; r < 4; ++r) { m_r[r] = -INFINITY; l_r[r] = 0.f; }

    const int NT = ib + 1;
    for (int tile = 0; tile < NT; ++tile) {
        const int cur = tile & 1;
        if (tile + 1 < NT)
            stage((tile + 1) << 6, cur ? 0 : 8192, cur ? 16384 : 24576);
        const char* ktb = smem + (cur ? 8192 : 0);
        const char* vtb = smem + (cur ? 24576 : 16384);

        // ---- QK^T ----
        float p[4][4];
        __builtin_amdgcn_s_setprio(1);
        f32x4 s[4];
        #pragma unroll
        for (int sub = 0; sub < 4; ++sub) {
            s[sub] = (f32x4)0.f;
            const int krow = sub * 16 + c;
            #pragma unroll
            for (int kh = 0; kh < 2; ++kh) {
                unsigned byte = ((unsigned)krow << 7) + ((unsigned)kh << 6) + ((unsigned)g << 4);
                byte ^= (unsigned)(krow & 7) << 4;
                bf16x8 kb = *(const bf16x8*)(ktb + byte);
                s[sub] = __builtin_amdgcn_mfma_f32_16x16x32_bf16(qa[kh], kb, s[sub], 0, 0, 0);
            }
        }
        __builtin_amdgcn_s_setprio(0);

        if (tile < ib - 1) {
            // ---- interior fast path: t17 == 0 everywhere ----
            #pragma unroll
            for (int sub = 0; sub < 4; ++sub)
                #pragma unroll
                for (int r = 0; r < 4; ++r)
                    p[sub][r] = s[sub][r] * 0.125f + qrel0s[r];
        } else {
            // ---- boundary fixup + tap capture ----
            #pragma unroll
            for (int sub = 0; sub < 4; ++sub) {
                const int dbase = (tile - ib) * 64 + (sub * 16 + c) - (w * 16 + g * 4);
                #pragma unroll
                for (int r = 0; r < 4; ++r) {
                    const int dj = dbase - r;
                    int t17 = dj + 16;
                    t17 = t17 < 0 ? 0 : (t17 > 16 ? 16 : t17);
                    const int il = w * 16 + g * 4 + r;
                    float sc = (s[sub][r] + b2f(qrelb[il * 20 + t17])) * 0.125f;
                    if (tile == ib && dj > 0) sc = -INFINITY;
                    p[sub][r] = sc;
                    if (dj >= -15 && dj <= 0)
                        tapss[il * 16 + dj + 15] = sc;
                }
            }
        }

        // ---- online softmax (rows live in 16-lane groups) ----
        #pragma unroll
        for (int r = 0; r < 4; ++r) {
            float mx = fmaxf(fmaxf(p[0][r], p[1][r]), fmaxf(p[2][r], p[3][r]));
            #pragma unroll
            for (int msk = 1; msk < 16; msk <<= 1)
                mx = fmaxf(mx, __shfl_xor(mx, msk));
            const float mn = fmaxf(m_r[r], mx);
            const float scale = __expf(m_r[r] - mn);
            m_r[r] = mn;
            float sum = 0.f;
            #pragma unroll
            for (int sub = 0; sub < 4; ++sub) {
                const float pe = __expf(p[sub][r] - mn);
                p[sub][r] = pe;
                sum += pe;
            }
            #pragma unroll
            for (int msk = 1; msk < 16; msk <<= 1)
                sum += __shfl_xor(sum, msk);
            l_r[r] = l_r[r] * scale + sum;
            #pragma unroll
            for (int dt = 0; dt < 4; ++dt) acc[dt][r] *= scale;
        }

        // ---- P -> per-wave LDS (bf16, swizzled) ----
        char* pw = pb + w * 2048;
        #pragma unroll
        for (int sub = 0; sub < 4; ++sub)
            #pragma unroll
            for (int r = 0; r < 4; ++r) {
                const int row = g * 4 + r;
                unsigned byte = ((unsigned)row << 7) + (((unsigned)(sub * 16 + c)) << 1);
                byte ^= (unsigned)(row & 7) << 4;
                *(short*)(pw + byte) = f2b(p[sub][r]);
            }

        // ---- PV ----
        bf16x8 pa[2];
        #pragma unroll
        for (int jh = 0; jh < 2; ++jh) {
            unsigned byte = ((unsigned)c << 7) + ((unsigned)jh << 6) + ((unsigned)g << 4);
            byte ^= (unsigned)(c & 7) << 4;
            pa[jh] = *(const bf16x8*)(pw + byte);
        }
        __builtin_amdgcn_s_setprio(1);
        #pragma unroll
        for (int dt = 0; dt < 4; ++dt) {
            const int d = dt * 16 + c;
            #pragma unroll
            for (int jh = 0; jh < 2; ++jh) {
                unsigned byte = ((unsigned)d << 7) + ((unsigned)jh << 6) + ((unsigned)g << 4);
                byte ^= (unsigned)(d & 7) << 4;
                bf16x8 vb = *(const bf16x8*)(vtb + byte);
                acc[dt] = __builtin_amdgcn_mfma_f32_16x16x32_bf16(pa[jh], vb, acc[dt], 0, 0, 0);
            }
        }
        __builtin_amdgcn_s_setprio(0);
        __syncthreads();
    }

    // ---- epilogue: taps + bin-0 residual + normalize + write ----
    const int rbase = w * 16 + g * 4;
    #pragma unroll
    for (int r = 0; r < 4; ++r) {
        const int il = rbase + r;
        const float mr = m_r[r];
        float c0 = l_r[r];
        float tp[16];
        #pragma unroll
        for (int tap = 0; tap < 16; ++tap) {
            const int jg = i0 + il + tap - 15;
            float pv = 0.f;
            if (jg >= 0) pv = __expf(tapss[il * 16 + tap] - mr);
            tp[tap] = pv;
            c0 -= pv;
        }
        const float invl = 1.f / l_r[r];
        #pragma unroll
        for (int dt = 0; dt < 4; ++dt) {
            const int d = dt * 16 + c;
            float o = acc[dt][r] + c0 * b2f(lvfb[d]);
            #pragma unroll
            for (int tap = 0; tap < 16; ++tap)
                o += tp[tap] * b2f(lvfb[(tap + 1) * 64 + d]);
            o *= invl;
            ao[((size_t)b * S_LEN + (i0 + il)) * D_MODEL + h * DK + d] = (USH)f2b(o);
        }
    }
}

// ---------------------------------------------------------------------------
extern "C" void kernel_launch(void* const* d_in, const int* in_sizes, int n_in,
                              void* d_out, int out_size, void* d_ws, size_t ws_size,
                              hipStream_t stream) {
    const float* x      = (const float*)d_in[0];
    const float* W_attn = (const float*)d_in[1];
    const float* b_attn = (const float*)d_in[2];
    const float* W_proj = (const float*)d_in[3];
    const float* b_proj = (const float*)d_in[4];
    const float* lut_k  = (const float*)d_in[5];
    const float* lut_v  = (const float*)d_in[6];
    float* out = (float*)d_out;

    // workspace layout (all USH)
    USH* qb    = (USH*)d_ws;            // 8M
    USH* kb    = qb + HSZ;              // 8M
    USH* vb    = kb + HSZ;              // 8M (row-major V)
    USH* vtg   = vb + HSZ;              // 8M (per-head transposed V)
    USH* aob   = vtg + HSZ;             // 8M
    USH* xb    = aob + HSZ;             // 8M
    USH* watt  = xb + HSZ;              // 3M
    USH* wproj = watt + 3145728;        // 1M

    // 0) conversions
    conv_bf16_kernel<<<HSZ / (256 * 8), 256, 0, stream>>>(x, xb);
    transp_bf16_kernel<<<dim3(3072 / 64, 1024 / 64), 256, 0, stream>>>(
        W_attn, watt, 1024, 3072);
    transp_bf16_kernel<<<dim3(1024 / 64, 1024 / 64), 256, 0, stream>>>(
        W_proj, wproj, 1024, 1024);

    // 1) QKV projection (bf16 MFMA)
    mfma_gemm_kernel<1><<<dim3(3072 / 128, 8192 / 128), 256, 0, stream>>>(
        xb, watt, b_attn, nullptr, qb, kb, vb, 8192, 3072, 1024);

    // 1b) per-head V transpose
    vtransp_kernel<<<2048, 256, 0, stream>>>(vb, vtg);

    // 2) attention
    attn_mfma_kernel<<<2048, 256, 0, stream>>>(qb, kb, vtg, lut_k, lut_v, aob);

    // 3) output projection (bf16 MFMA)
    mfma_gemm_kernel<0><<<dim3(1024 / 128, 8192 / 128), 256, 0, stream>>>(
        aob, wproj, b_proj, out, nullptr, nullptr, nullptr, 8192, 1024, 1024);
}

// Round 8
// 209.384 us; speedup vs baseline: 13.7641x; 1.1710x over previous
//
#include <hip/hip_runtime.h>
#include <hip/hip_bf16.h>
#include <math.h>

#define NH 16
#define S_LEN 1024
#define DK 64
#define D_MODEL 1024
#define HSZ 8388608          // B*NH*S*DK elements per q/k/v buffer

typedef __attribute__((ext_vector_type(8))) short bf16x8;
typedef __attribute__((ext_vector_type(4))) float f32x4;
typedef unsigned short USH;

#define EXPSCALE 0.1803368801111204f   // 0.125 * log2(e)

__device__ __forceinline__ float fast_exp2(float x) {
    return __builtin_amdgcn_exp2f(x);
}

__device__ __forceinline__ short f2b(float x) {
    union { __hip_bfloat16 h; short s; } u;
    u.h = __float2bfloat16(x);
    return u.s;
}
__device__ __forceinline__ float b2f(USH u) {
    union { unsigned i; float f; } x;
    x.i = (unsigned)u << 16;
    return x.f;
}

__device__ __forceinline__ void gload16(const void* src, void* lds) {
    __builtin_amdgcn_global_load_lds(
        (const __attribute__((address_space(1))) void*)src,
        (__attribute__((address_space(3))) void*)lds,
        16, 0, 0);
}

// ---------------------------------------------------------------------------
// fp32 -> bf16 conversion (exact-grid, 8 elems/thread)
// ---------------------------------------------------------------------------
__global__ __launch_bounds__(256)
void conv_bf16_kernel(const float* __restrict__ in, USH* __restrict__ out) {
    const int i = (blockIdx.x * 256 + threadIdx.x) * 8;
    const float4 a = *(const float4*)&in[i];
    const float4 b = *(const float4*)&in[i + 4];
    ushort4 o0, o1;
    o0.x = (USH)f2b(a.x); o0.y = (USH)f2b(a.y); o0.z = (USH)f2b(a.z); o0.w = (USH)f2b(a.w);
    o1.x = (USH)f2b(b.x); o1.y = (USH)f2b(b.y); o1.z = (USH)f2b(b.z); o1.w = (USH)f2b(b.w);
    *(ushort4*)&out[i] = o0;
    *(ushort4*)&out[i + 4] = o1;
}

// ---------------------------------------------------------------------------
// Transpose + convert: in [R][C] fp32 -> out [C][R] bf16. 64x64 tiles.
// ---------------------------------------------------------------------------
__global__ __launch_bounds__(256)
void transp_bf16_kernel(const float* __restrict__ in, USH* __restrict__ out,
                        int R, int C) {
    __shared__ USH Ts[64][65];
    const int r0 = blockIdx.y * 64, c0 = blockIdx.x * 64;
    const int tr = threadIdx.x >> 4;
    const int tc4 = (threadIdx.x & 15) * 4;
    #pragma unroll
    for (int ph = 0; ph < 4; ++ph) {
        const int r = ph * 16 + tr;
        const float4 v = *(const float4*)&in[(size_t)(r0 + r) * C + c0 + tc4];
        Ts[tc4 + 0][r] = (USH)f2b(v.x);
        Ts[tc4 + 1][r] = (USH)f2b(v.y);
        Ts[tc4 + 2][r] = (USH)f2b(v.z);
        Ts[tc4 + 3][r] = (USH)f2b(v.w);
    }
    __syncthreads();
    #pragma unroll
    for (int ph = 0; ph < 4; ++ph) {
        const int cc = ph * 16 + tr;
        ushort4 o;
        o.x = Ts[cc][tc4 + 0]; o.y = Ts[cc][tc4 + 1];
        o.z = Ts[cc][tc4 + 2]; o.w = Ts[cc][tc4 + 3];
        *(ushort4*)&out[(size_t)(c0 + cc) * R + r0 + tc4] = o;
    }
}

// ---------------------------------------------------------------------------
// Per-head V transpose (bf16): in [bh][s][64] -> out [bh][d=64][s=1024]
// ---------------------------------------------------------------------------
__global__ __launch_bounds__(256)
void vtransp_kernel(const USH* __restrict__ in, USH* __restrict__ out) {
    __shared__ USH T[64][72];
    const int bh = blockIdx.x >> 4;
    const int s0 = (blockIdx.x & 15) * 64;
    const int r = threadIdx.x >> 4;
    const int c4 = (threadIdx.x & 15) * 4;
    #pragma unroll
    for (int ph = 0; ph < 4; ++ph) {
        const int row = ph * 16 + r;   // s offset
        const ushort4 v = *(const ushort4*)
            &in[((size_t)bh * S_LEN + s0 + row) * DK + c4];
        T[row][c4 + 0] = v.x; T[row][c4 + 1] = v.y;
        T[row][c4 + 2] = v.z; T[row][c4 + 3] = v.w;
    }
    __syncthreads();
    #pragma unroll
    for (int ph = 0; ph < 4; ++ph) {
        const int d = ph * 16 + r;
        ushort4 o;
        o.x = T[c4 + 0][d]; o.y = T[c4 + 1][d];
        o.z = T[c4 + 2][d]; o.w = T[c4 + 3][d];
        *(ushort4*)&out[(size_t)bh * (S_LEN * DK) + (size_t)d * S_LEN + s0 + c4] = o;
    }
}

// ---------------------------------------------------------------------------
// bf16 MFMA GEMM (m97 structure) — q/k/v written bf16 when QKV=1.
// ---------------------------------------------------------------------------
template<int QKV>
__global__ __launch_bounds__(256)
void mfma_gemm_kernel(const USH* __restrict__ A, const USH* __restrict__ Bt,
                      const float* __restrict__ bias,
                      float* __restrict__ Cf, USH* __restrict__ Cq,
                      USH* __restrict__ Ck, USH* __restrict__ Cv,
                      int M, int N, int K) {
    __shared__ __align__(16) USH As[128 * 32];
    __shared__ __align__(16) USH Bs[128 * 32];
    const int t = threadIdx.x;
    const int w = t >> 6, lane = t & 63, g = lane >> 4, c = lane & 15;
    const int wm = w >> 1, wn = w & 1;
    const int bm0 = blockIdx.y * 128, bn0 = blockIdx.x * 128;

    const int sk = ((t & 3) ^ ((t >> 3) & 3)) * 8;
    const USH* pa0 = A + (size_t)(bm0 + (t >> 2)) * K + sk;
    const USH* pa1 = pa0 + (size_t)64 * K;
    const USH* pb0 = Bt + (size_t)(bn0 + (t >> 2)) * K + sk;
    const USH* pb1 = pb0 + (size_t)64 * K;
    USH* ldsA0 = &As[(t & ~63) * 8];
    USH* ldsA1 = ldsA0 + 2048;
    USH* ldsB0 = &Bs[(t & ~63) * 8];
    USH* ldsB1 = ldsB0 + 2048;

    unsigned aoff[4], boff[4];
    #pragma unroll
    for (int i = 0; i < 4; ++i) {
        const int r = wm * 64 + i * 16 + c;
        aoff[i] = ((unsigned)(r * 64 + g * 16)) ^ ((((unsigned)r >> 1) & 3) << 4);
        const int n = wn * 64 + i * 16 + c;
        boff[i] = ((unsigned)(n * 64 + g * 16)) ^ ((((unsigned)n >> 1) & 3) << 4);
    }

    f32x4 acc[4][4];
    #pragma unroll
    for (int i = 0; i < 4; ++i)
        #pragma unroll
        for (int j = 0; j < 4; ++j) acc[i][j] = (f32x4)0.f;

    for (int k0 = 0; k0 < K; k0 += 32) {
        gload16(pa0 + k0, ldsA0);
        gload16(pa1 + k0, ldsA1);
        gload16(pb0 + k0, ldsB0);
        gload16(pb1 + k0, ldsB1);
        __syncthreads();

        bf16x8 af[4], bfr[4];
        #pragma unroll
        for (int i = 0; i < 4; ++i) af[i] = *(const bf16x8*)((const char*)As + aoff[i]);
        #pragma unroll
        for (int j = 0; j < 4; ++j) bfr[j] = *(const bf16x8*)((const char*)Bs + boff[j]);
        #pragma unroll
        for (int i = 0; i < 4; ++i)
            #pragma unroll
            for (int j = 0; j < 4; ++j)
                acc[i][j] = __builtin_amdgcn_mfma_f32_16x16x32_bf16(
                    af[i], bfr[j], acc[i][j], 0, 0, 0);
        __syncthreads();
    }

    #pragma unroll
    for (int i = 0; i < 4; ++i) {
        #pragma unroll
        for (int reg = 0; reg < 4; ++reg) {
            const int m = bm0 + wm * 64 + i * 16 + g * 4 + reg;
            #pragma unroll
            for (int j = 0; j < 4; ++j) {
                const int n = bn0 + wn * 64 + j * 16 + c;
                const float v = acc[i][j][reg] + bias[n];
                if (QKV) {
                    const int which = n >> 10;
                    const int h = (n & 1023) >> 6, d = n & 63;
                    const int b = m >> 10, s = m & 1023;
                    const size_t idx = (((size_t)(b * NH + h)) * S_LEN + s) * DK + d;
                    if (which == 0)      Cq[idx] = (USH)f2b(v);
                    else if (which == 1) Ck[idx] = (USH)f2b(v);
                    else                 Cv[idx] = (USH)f2b(v);
                } else {
                    Cf[(size_t)m * N + n] = v;
                }
            }
        }
    }
}

// ---------------------------------------------------------------------------
// MFMA flash attention, double-buffered async staging.
// Fixed-shift softmax (shift-invariance): p = exp2((qk+qrel)*C); no max
// tracking, no rescale; per-lane partial sums reduced once in the epilogue.
// Scores bounded (|s| small) so fp32 range is safe.
// ---------------------------------------------------------------------------
__global__ __launch_bounds__(256, 3)
void attn_mfma_kernel(const USH* __restrict__ qb,
                      const USH* __restrict__ kbuf,
                      const USH* __restrict__ vtg,
                      const float* __restrict__ lut_k,
                      const float* __restrict__ lut_v,
                      USH* __restrict__ ao) {
    const int bid = blockIdx.x;
    const int logical = (bid & 7) * 256 + (bid >> 3);   // XCD-contiguous bh
    const int ib = logical & 15;
    const int bh = logical >> 4;
    const int b = bh >> 4, h = bh & 15;
    const int i0 = ib * 64;
    const int t = threadIdx.x;
    const int w = t >> 6;
    const int lane = t & 63;
    const int g = lane >> 4;
    const int c = lane & 15;

    __shared__ __align__(16) char smem[49792];
    char* qsb   = smem + 8192;               // aliases ktb1 (phase 0 only)
    char* pb    = smem + 32768;
    char* lutkb = smem + 32768;              // aliases pb (phase 0 only)
    USH* qrelb  = (USH*)(smem + 40960);      // [64][20] bf16 (raw qrel)
    USH* lvfb   = (USH*)(smem + 43520);      // [17][64] bf16
    float* tapss = (float*)(smem + 45696);   // [64][16]  p values

    const USH* qp  = qb   + (size_t)bh * (S_LEN * DK);
    const USH* kp  = kbuf + (size_t)bh * (S_LEN * DK);
    const USH* vtp = vtg  + (size_t)bh * (S_LEN * DK);  // [d=64][s=1024]

    // async stage of one 64x64 K tile + V^T tile into (koff,voff)
    auto stage = [&](int j0, int koff, int voff) {
        #pragma unroll
        for (int qq = 0; qq < 2; ++qq) {
            const int o = (w * 2 + qq) * 1024 + lane * 16;
            const int row = o >> 7;
            const int chunk = (o >> 4) & 7;
            const int sc = (chunk ^ (row & 7)) * 8;
            gload16(kp + (size_t)(j0 + row) * DK + sc,
                    smem + koff + (w * 2 + qq) * 1024);
            gload16(vtp + (size_t)row * S_LEN + j0 + sc,
                    smem + voff + (w * 2 + qq) * 1024);
        }
    };

    // ---- phase 0: issue tile-0 loads; stage q (bf16, swizzled) + LUTs ----
    stage(0, 0, 16384);
    for (int f = t; f < 1024; f += 256) {
        const int row = f >> 4, c4 = (f & 15) * 4;
        unsigned byte = ((unsigned)(row * 128 + c4 * 2)) ^ (((unsigned)row & 7) << 4);
        *(ushort4*)(qsb + byte) = *(const ushort4*)&qp[(size_t)(i0 + row) * DK + c4];
    }
    // lut_k -> bf16 LDS [32][64], rows 17..31 zero, swizzled
    for (int e = t; e < 32 * 64; e += 256) {
        const int row = e >> 6, d = e & 63;
        const USH v = (row < 17) ? (USH)f2b(lut_k[row * 64 + d]) : (USH)0;
        unsigned byte = ((unsigned)(row * 128 + d * 2)) ^ (((unsigned)row & 7) << 4);
        *(USH*)(lutkb + byte) = v;
    }
    for (int e = t; e < 17 * 64; e += 256)
        lvfb[e] = (USH)f2b(lut_v[e]);
    __syncthreads();   // drains tile-0 gloads too

    // Q fragments straight from swizzled bf16 LDS
    bf16x8 qa[2];
    {
        const int row = w * 16 + c;
        #pragma unroll
        for (int kh = 0; kh < 2; ++kh) {
            unsigned byte = ((unsigned)(row * 128 + kh * 64 + g * 16))
                          ^ (((unsigned)row & 7) << 4);
            qa[kh] = *(const bf16x8*)(qsb + byte);
        }
    }

    // qrel via MFMA: lut_k rows as 17 virtual keys (2 col sub-tiles)
    {
        f32x4 qr[2];
        qr[0] = (f32x4)0.f; qr[1] = (f32x4)0.f;
        #pragma unroll
        for (int sub2 = 0; sub2 < 2; ++sub2) {
            const int tap = sub2 * 16 + c;
            #pragma unroll
            for (int kh = 0; kh < 2; ++kh) {
                unsigned byte = ((unsigned)(tap * 128 + kh * 64 + g * 16))
                              ^ (((unsigned)tap & 7) << 4);
                bf16x8 lb = *(const bf16x8*)(lutkb + byte);
                qr[sub2] = __builtin_amdgcn_mfma_f32_16x16x32_bf16(
                    qa[kh], lb, qr[sub2], 0, 0, 0);
            }
        }
        #pragma unroll
        for (int sub2 = 0; sub2 < 2; ++sub2) {
            const int tap = sub2 * 16 + c;
            if (tap < 17) {
                #pragma unroll
                for (int r = 0; r < 4; ++r)
                    qrelb[(w * 16 + g * 4 + r) * 20 + tap] = (USH)f2b(qr[sub2][r]);
            }
        }
    }
    __syncthreads();   // qsb/lutkb dead; qrelb ready; pb free for P

    // hoist tap-0 qrel (pre-scaled by EXPSCALE) for interior tiles
    float qrel0s[4];
    #pragma unroll
    for (int r = 0; r < 4; ++r)
        qrel0s[r] = b2f(qrelb[(w * 16 + g * 4 + r) * 20]) * EXPSCALE;

    f32x4 acc[4];
    #pragma unroll
    for (int dt = 0; dt < 4; ++dt) acc[dt] = (f32x4)0.f;
    float l_r[4];   // per-lane PARTIAL row sums (reduced in epilogue)
    #pragma unroll
    for (int r = 0; r < 4; ++r) l_r[r] = 0.f;

    const int NT = ib + 1;
    for (int tile = 0; tile < NT; ++tile) {
        const int cur = tile & 1;
        if (tile + 1 < NT)
            stage((tile + 1) << 6, cur ? 0 : 8192, cur ? 16384 : 24576);
        const char* ktb = smem + (cur ? 8192 : 0);
        const char* vtb = smem + (cur ? 24576 : 16384);

        // ---- QK^T ----
        float p[4][4];
        __builtin_amdgcn_s_setprio(1);
        f32x4 s[4];
        #pragma unroll
        for (int sub = 0; sub < 4; ++sub) {
            s[sub] = (f32x4)0.f;
            const int krow = sub * 16 + c;
            #pragma unroll
            for (int kh = 0; kh < 2; ++kh) {
                unsigned byte = ((unsigned)krow << 7) + ((unsigned)kh << 6) + ((unsigned)g << 4);
                byte ^= (unsigned)(krow & 7) << 4;
                bf16x8 kb = *(const bf16x8*)(ktb + byte);
                s[sub] = __builtin_amdgcn_mfma_f32_16x16x32_bf16(qa[kh], kb, s[sub], 0, 0, 0);
            }
        }
        __builtin_amdgcn_s_setprio(0);

        if (tile < ib - 1) {
            // ---- interior fast path: tap index 0 everywhere ----
            #pragma unroll
            for (int sub = 0; sub < 4; ++sub)
                #pragma unroll
                for (int r = 0; r < 4; ++r)
                    p[sub][r] = fast_exp2(s[sub][r] * EXPSCALE + qrel0s[r]);
        } else {
            // ---- boundary: clamped tap lookup + causal mask + tap capture ----
            #pragma unroll
            for (int sub = 0; sub < 4; ++sub) {
                const int dbase = (tile - ib) * 64 + (sub * 16 + c) - (w * 16 + g * 4);
                #pragma unroll
                for (int r = 0; r < 4; ++r) {
                    const int dj = dbase - r;
                    int t17 = dj + 16;
                    t17 = t17 < 0 ? 0 : (t17 > 16 ? 16 : t17);
                    const int il = w * 16 + g * 4 + r;
                    float pv = fast_exp2((s[sub][r] + b2f(qrelb[il * 20 + t17])) * EXPSCALE);
                    if (tile == ib && dj > 0) pv = 0.f;
                    p[sub][r] = pv;
                    if (dj >= -15 && dj <= 0)
                        tapss[il * 16 + dj + 15] = pv;
                }
            }
        }

        // ---- accumulate per-lane partial row sums (no cross-lane ops) ----
        #pragma unroll
        for (int r = 0; r < 4; ++r)
            l_r[r] += (p[0][r] + p[1][r]) + (p[2][r] + p[3][r]);

        // ---- P -> per-wave LDS (bf16, swizzled) ----
        char* pw = pb + w * 2048;
        #pragma unroll
        for (int sub = 0; sub < 4; ++sub)
            #pragma unroll
            for (int r = 0; r < 4; ++r) {
                const int row = g * 4 + r;
                unsigned byte = ((unsigned)row << 7) + (((unsigned)(sub * 16 + c)) << 1);
                byte ^= (unsigned)(row & 7) << 4;
                *(short*)(pw + byte) = f2b(p[sub][r]);
            }

        // ---- PV ----
        bf16x8 pa[2];
        #pragma unroll
        for (int jh = 0; jh < 2; ++jh) {
            unsigned byte = ((unsigned)c << 7) + ((unsigned)jh << 6) + ((unsigned)g << 4);
            byte ^= (unsigned)(c & 7) << 4;
            pa[jh] = *(const bf16x8*)(pw + byte);
        }
        __builtin_amdgcn_s_setprio(1);
        #pragma unroll
        for (int dt = 0; dt < 4; ++dt) {
            const int d = dt * 16 + c;
            #pragma unroll
            for (int jh = 0; jh < 2; ++jh) {
                unsigned byte = ((unsigned)d << 7) + ((unsigned)jh << 6) + ((unsigned)g << 4);
                byte ^= (unsigned)(d & 7) << 4;
                bf16x8 vb = *(const bf16x8*)(vtb + byte);
                acc[dt] = __builtin_amdgcn_mfma_f32_16x16x32_bf16(pa[jh], vb, acc[dt], 0, 0, 0);
            }
        }
        __builtin_amdgcn_s_setprio(0);
        __syncthreads();
    }

    // ---- epilogue: reduce row sums, taps + bin-0 residual, write ----
    const int rbase = w * 16 + g * 4;
    #pragma unroll
    for (int r = 0; r < 4; ++r) {
        float lsum = l_r[r];
        #pragma unroll
        for (int msk = 1; msk < 16; msk <<= 1)
            lsum += __shfl_xor(lsum, msk);
        const int il = rbase + r;
        float c0 = lsum;
        float tp[16];
        #pragma unroll
        for (int tap = 0; tap < 16; ++tap) {
            const int jg = i0 + il + tap - 15;
            const float pv = (jg >= 0) ? tapss[il * 16 + tap] : 0.f;
            tp[tap] = pv;
            c0 -= pv;
        }
        const float invl = 1.f / lsum;
        #pragma unroll
        for (int dt = 0; dt < 4; ++dt) {
            const int d = dt * 16 + c;
            float o = acc[dt][r] + c0 * b2f(lvfb[d]);
            #pragma unroll
            for (int tap = 0; tap < 16; ++tap)
                o += tp[tap] * b2f(lvfb[(tap + 1) * 64 + d]);
            o *= invl;
            ao[((size_t)b * S_LEN + (i0 + il)) * D_MODEL + h * DK + d] = (USH)f2b(o);
        }
    }
}

// ---------------------------------------------------------------------------
extern "C" void kernel_launch(void* const* d_in, const int* in_sizes, int n_in,
                              void* d_out, int out_size, void* d_ws, size_t ws_size,
                              hipStream_t stream) {
    const float* x      = (const float*)d_in[0];
    const float* W_attn = (const float*)d_in[1];
    const float* b_attn = (const float*)d_in[2];
    const float* W_proj = (const float*)d_in[3];
    const float* b_proj = (const float*)d_in[4];
    const float* lut_k  = (const float*)d_in[5];
    const float* lut_v  = (const float*)d_in[6];
    float* out = (float*)d_out;

    // workspace layout (all USH)
    USH* qb    = (USH*)d_ws;            // 8M
    USH* kb    = qb + HSZ;              // 8M
    USH* vb    = kb + HSZ;              // 8M (row-major V)
    USH* vtg   = vb + HSZ;              // 8M (per-head transposed V)
    USH* aob   = vtg + HSZ;             // 8M
    USH* xb    = aob + HSZ;             // 8M
    USH* watt  = xb + HSZ;              // 3M
    USH* wproj = watt + 3145728;        // 1M

    // 0) conversions
    conv_bf16_kernel<<<HSZ / (256 * 8), 256, 0, stream>>>(x, xb);
    transp_bf16_kernel<<<dim3(3072 / 64, 1024 / 64), 256, 0, stream>>>(
        W_attn, watt, 1024, 3072);
    transp_bf16_kernel<<<dim3(1024 / 64, 1024 / 64), 256, 0, stream>>>(
        W_proj, wproj, 1024, 1024);

    // 1) QKV projection (bf16 MFMA)
    mfma_gemm_kernel<1><<<dim3(3072 / 128, 8192 / 128), 256, 0, stream>>>(
        xb, watt, b_attn, nullptr, qb, kb, vb, 8192, 3072, 1024);

    // 1b) per-head V transpose
    vtransp_kernel<<<2048, 256, 0, stream>>>(vb, vtg);

    // 2) attention
    attn_mfma_kernel<<<2048, 256, 0, stream>>>(qb, kb, vtg, lut_k, lut_v, aob);

    // 3) output projection (bf16 MFMA)
    mfma_gemm_kernel<0><<<dim3(1024 / 128, 8192 / 128), 256, 0, stream>>>(
        aob, wproj, b_proj, out, nullptr, nullptr, nullptr, 8192, 1024, 1024);
}

// Round 9
// 206.835 us; speedup vs baseline: 13.9337x; 1.0123x over previous
//
#include <hip/hip_runtime.h>
#include <hip/hip_bf16.h>
#include <math.h>

#define NH 16
#define S_LEN 1024
#define DK 64
#define D_MODEL 1024
#define HSZ 8388608          // B*NH*S*DK elements per q/k/v buffer

typedef __attribute__((ext_vector_type(8))) short bf16x8;
typedef __attribute__((ext_vector_type(4))) float f32x4;
typedef unsigned short USH;

#define EXPSCALE 0.1803368801111204f   // 0.125 * log2(e)

__device__ __forceinline__ float fast_exp2(float x) {
    return __builtin_amdgcn_exp2f(x);
}

__device__ __forceinline__ short f2b(float x) {
    union { __hip_bfloat16 h; short s; } u;
    u.h = __float2bfloat16(x);
    return u.s;
}
__device__ __forceinline__ float b2f(USH u) {
    union { unsigned i; float f; } x;
    x.i = (unsigned)u << 16;
    return x.f;
}

__device__ __forceinline__ void gload16(const void* src, void* lds) {
    __builtin_amdgcn_global_load_lds(
        (const __attribute__((address_space(1))) void*)src,
        (__attribute__((address_space(3))) void*)lds,
        16, 0, 0);
}

// ---------------------------------------------------------------------------
// fp32 -> bf16 conversion (exact-grid, 8 elems/thread)
// ---------------------------------------------------------------------------
__global__ __launch_bounds__(256)
void conv_bf16_kernel(const float* __restrict__ in, USH* __restrict__ out) {
    const int i = (blockIdx.x * 256 + threadIdx.x) * 8;
    const float4 a = *(const float4*)&in[i];
    const float4 b = *(const float4*)&in[i + 4];
    ushort4 o0, o1;
    o0.x = (USH)f2b(a.x); o0.y = (USH)f2b(a.y); o0.z = (USH)f2b(a.z); o0.w = (USH)f2b(a.w);
    o1.x = (USH)f2b(b.x); o1.y = (USH)f2b(b.y); o1.z = (USH)f2b(b.z); o1.w = (USH)f2b(b.w);
    *(ushort4*)&out[i] = o0;
    *(ushort4*)&out[i + 4] = o1;
}

// ---------------------------------------------------------------------------
// Transpose + convert: in [R][C] fp32 -> out [C][R] bf16. 64x64 tiles.
// ---------------------------------------------------------------------------
__global__ __launch_bounds__(256)
void transp_bf16_kernel(const float* __restrict__ in, USH* __restrict__ out,
                        int R, int C) {
    __shared__ USH Ts[64][65];
    const int r0 = blockIdx.y * 64, c0 = blockIdx.x * 64;
    const int tr = threadIdx.x >> 4;
    const int tc4 = (threadIdx.x & 15) * 4;
    #pragma unroll
    for (int ph = 0; ph < 4; ++ph) {
        const int r = ph * 16 + tr;
        const float4 v = *(const float4*)&in[(size_t)(r0 + r) * C + c0 + tc4];
        Ts[tc4 + 0][r] = (USH)f2b(v.x);
        Ts[tc4 + 1][r] = (USH)f2b(v.y);
        Ts[tc4 + 2][r] = (USH)f2b(v.z);
        Ts[tc4 + 3][r] = (USH)f2b(v.w);
    }
    __syncthreads();
    #pragma unroll
    for (int ph = 0; ph < 4; ++ph) {
        const int cc = ph * 16 + tr;
        ushort4 o;
        o.x = Ts[cc][tc4 + 0]; o.y = Ts[cc][tc4 + 1];
        o.z = Ts[cc][tc4 + 2]; o.w = Ts[cc][tc4 + 3];
        *(ushort4*)&out[(size_t)(c0 + cc) * R + r0 + tc4] = o;
    }
}

// ---------------------------------------------------------------------------
// Per-head V transpose (bf16): in [bh][s][64] -> out [bh][d=64][s=1024]
// ---------------------------------------------------------------------------
__global__ __launch_bounds__(256)
void vtransp_kernel(const USH* __restrict__ in, USH* __restrict__ out) {
    __shared__ USH T[64][72];
    const int bh = blockIdx.x >> 4;
    const int s0 = (blockIdx.x & 15) * 64;
    const int r = threadIdx.x >> 4;
    const int c4 = (threadIdx.x & 15) * 4;
    #pragma unroll
    for (int ph = 0; ph < 4; ++ph) {
        const int row = ph * 16 + r;   // s offset
        const ushort4 v = *(const ushort4*)
            &in[((size_t)bh * S_LEN + s0 + row) * DK + c4];
        T[row][c4 + 0] = v.x; T[row][c4 + 1] = v.y;
        T[row][c4 + 2] = v.z; T[row][c4 + 3] = v.w;
    }
    __syncthreads();
    #pragma unroll
    for (int ph = 0; ph < 4; ++ph) {
        const int d = ph * 16 + r;
        ushort4 o;
        o.x = T[c4 + 0][d]; o.y = T[c4 + 1][d];
        o.z = T[c4 + 2][d]; o.w = T[c4 + 3][d];
        *(ushort4*)&out[(size_t)bh * (S_LEN * DK) + (size_t)d * S_LEN + s0 + c4] = o;
    }
}

// ---------------------------------------------------------------------------
// bf16 MFMA GEMM (m97 structure) — q/k/v written bf16 when QKV=1.
// ---------------------------------------------------------------------------
template<int QKV>
__global__ __launch_bounds__(256)
void mfma_gemm_kernel(const USH* __restrict__ A, const USH* __restrict__ Bt,
                      const float* __restrict__ bias,
                      float* __restrict__ Cf, USH* __restrict__ Cq,
                      USH* __restrict__ Ck, USH* __restrict__ Cv,
                      int M, int N, int K) {
    __shared__ __align__(16) USH As[128 * 32];
    __shared__ __align__(16) USH Bs[128 * 32];
    const int t = threadIdx.x;
    const int w = t >> 6, lane = t & 63, g = lane >> 4, c = lane & 15;
    const int wm = w >> 1, wn = w & 1;
    const int bm0 = blockIdx.y * 128, bn0 = blockIdx.x * 128;

    const int sk = ((t & 3) ^ ((t >> 3) & 3)) * 8;
    const USH* pa0 = A + (size_t)(bm0 + (t >> 2)) * K + sk;
    const USH* pa1 = pa0 + (size_t)64 * K;
    const USH* pb0 = Bt + (size_t)(bn0 + (t >> 2)) * K + sk;
    const USH* pb1 = pb0 + (size_t)64 * K;
    USH* ldsA0 = &As[(t & ~63) * 8];
    USH* ldsA1 = ldsA0 + 2048;
    USH* ldsB0 = &Bs[(t & ~63) * 8];
    USH* ldsB1 = ldsB0 + 2048;

    unsigned aoff[4], boff[4];
    #pragma unroll
    for (int i = 0; i < 4; ++i) {
        const int r = wm * 64 + i * 16 + c;
        aoff[i] = ((unsigned)(r * 64 + g * 16)) ^ ((((unsigned)r >> 1) & 3) << 4);
        const int n = wn * 64 + i * 16 + c;
        boff[i] = ((unsigned)(n * 64 + g * 16)) ^ ((((unsigned)n >> 1) & 3) << 4);
    }

    f32x4 acc[4][4];
    #pragma unroll
    for (int i = 0; i < 4; ++i)
        #pragma unroll
        for (int j = 0; j < 4; ++j) acc[i][j] = (f32x4)0.f;

    for (int k0 = 0; k0 < K; k0 += 32) {
        gload16(pa0 + k0, ldsA0);
        gload16(pa1 + k0, ldsA1);
        gload16(pb0 + k0, ldsB0);
        gload16(pb1 + k0, ldsB1);
        __syncthreads();

        bf16x8 af[4], bfr[4];
        #pragma unroll
        for (int i = 0; i < 4; ++i) af[i] = *(const bf16x8*)((const char*)As + aoff[i]);
        #pragma unroll
        for (int j = 0; j < 4; ++j) bfr[j] = *(const bf16x8*)((const char*)Bs + boff[j]);
        #pragma unroll
        for (int i = 0; i < 4; ++i)
            #pragma unroll
            for (int j = 0; j < 4; ++j)
                acc[i][j] = __builtin_amdgcn_mfma_f32_16x16x32_bf16(
                    af[i], bfr[j], acc[i][j], 0, 0, 0);
        __syncthreads();
    }

    #pragma unroll
    for (int i = 0; i < 4; ++i) {
        #pragma unroll
        for (int reg = 0; reg < 4; ++reg) {
            const int m = bm0 + wm * 64 + i * 16 + g * 4 + reg;
            #pragma unroll
            for (int j = 0; j < 4; ++j) {
                const int n = bn0 + wn * 64 + j * 16 + c;
                const float v = acc[i][j][reg] + bias[n];
                if (QKV) {
                    const int which = n >> 10;
                    const int h = (n & 1023) >> 6, d = n & 63;
                    const int b = m >> 10, s = m & 1023;
                    const size_t idx = (((size_t)(b * NH + h)) * S_LEN + s) * DK + d;
                    if (which == 0)      Cq[idx] = (USH)f2b(v);
                    else if (which == 1) Ck[idx] = (USH)f2b(v);
                    else                 Cv[idx] = (USH)f2b(v);
                } else {
                    Cf[(size_t)m * N + n] = v;
                }
            }
        }
    }
}

// ---------------------------------------------------------------------------
// MFMA flash attention: 8 waves x 128 q-rows per block, KVBLK=64, dbuf async
// staging. Fixed-shift softmax (no max tracking, no rescale); per-lane
// partial sums reduced once in the epilogue.
// LDS map (64640 B -> 2 blocks/CU):
//   0      ktb0  8KB
//   8192   ktb1  8KB
//   16384  vtb0  8KB
//   24576  vtb1  8KB
//   32768  pb    16KB (8 waves x 2KB)   (phase0: q bf16 [128][64] swizzled)
//   49152  qrelb bf16 [128][20]  5120B
//   54272  lvfb  bf16 [17][64]   2176B
//   56448  tapss f32  [128][16]  8192B  (phase0: lut_k bf16 [32][64] swz 4KB)
// Swizzle involution: 16B-chunk ^= (row&7); applied to global SOURCE for
// global_load_lds (LDS linear) and to the ds_read side.
// Interior iff tile < NT-3 (then dj <= -65); boundary path masks dj>0
// per-element (diagonal spans two tiles with 128 q-rows).
// ---------------------------------------------------------------------------
__global__ __launch_bounds__(512, 4)
void attn_mfma_kernel(const USH* __restrict__ qb,
                      const USH* __restrict__ kbuf,
                      const USH* __restrict__ vtg,
                      const float* __restrict__ lut_k,
                      const float* __restrict__ lut_v,
                      USH* __restrict__ ao) {
    const int bid = blockIdx.x;
    const int logical = (bid & 7) * 128 + (bid >> 3);   // XCD-contiguous bh
    const int ib = logical & 7;
    const int bh = logical >> 3;
    const int b = bh >> 4, h = bh & 15;
    const int i0 = ib * 128;
    const int t = threadIdx.x;
    const int w = t >> 6;          // 0..7
    const int lane = t & 63;
    const int g = lane >> 4;
    const int c = lane & 15;

    __shared__ __align__(16) char smem[64640];
    char* pb    = smem + 32768;              // P buffers (main loop)
    char* qsb   = smem + 32768;              // phase0 alias: q [128][64] swz
    char* lutkb = smem + 56448;              // phase0 alias of tapss
    USH* qrelb  = (USH*)(smem + 49152);      // [128][20] bf16
    USH* lvfb   = (USH*)(smem + 54272);      // [17][64] bf16
    float* tapss = (float*)(smem + 56448);   // [128][16] p values

    const USH* qp  = qb   + (size_t)bh * (S_LEN * DK);
    const USH* kp  = kbuf + (size_t)bh * (S_LEN * DK);
    const USH* vtp = vtg  + (size_t)bh * (S_LEN * DK);  // [d=64][s=1024]

    // async stage of one 64x64 K tile + V^T tile (512 thr = 1 gload16 each)
    auto stage = [&](int j0, int koff, int voff) {
        const int o = t * 16;
        const int row = o >> 7;
        const int chunk = (o >> 4) & 7;
        const int sc = (chunk ^ (row & 7)) * 8;
        gload16(kp + (size_t)(j0 + row) * DK + sc, smem + koff + o);
        gload16(vtp + (size_t)row * S_LEN + j0 + sc, smem + voff + o);
    };

    // ---- phase 0: issue tile-0 loads; stage q (bf16, swizzled) + LUTs ----
    stage(0, 0, 16384);
    for (int f = t; f < 2048; f += 512) {
        const int row = f >> 4, c4 = (f & 15) * 4;
        unsigned byte = ((unsigned)(row * 128 + c4 * 2)) ^ (((unsigned)row & 7) << 4);
        *(ushort4*)(qsb + byte) = *(const ushort4*)&qp[(size_t)(i0 + row) * DK + c4];
    }
    // lut_k -> bf16 LDS [32][64], rows 17..31 zero, swizzled
    for (int e = t; e < 32 * 64; e += 512) {
        const int row = e >> 6, d = e & 63;
        const USH v = (row < 17) ? (USH)f2b(lut_k[row * 64 + d]) : (USH)0;
        unsigned byte = ((unsigned)(row * 128 + d * 2)) ^ (((unsigned)row & 7) << 4);
        *(USH*)(lutkb + byte) = v;
    }
    for (int e = t; e < 17 * 64; e += 512)
        lvfb[e] = (USH)f2b(lut_v[e]);
    __syncthreads();   // drains tile-0 gloads too

    // Q fragments straight from swizzled bf16 LDS (wave w owns rows w*16..+15)
    bf16x8 qa[2];
    {
        const int row = w * 16 + c;
        #pragma unroll
        for (int kh = 0; kh < 2; ++kh) {
            unsigned byte = ((unsigned)(row * 128 + kh * 64 + g * 16))
                          ^ (((unsigned)row & 7) << 4);
            qa[kh] = *(const bf16x8*)(qsb + byte);
        }
    }

    // qrel via MFMA: lut_k rows as 17 virtual keys (2 col sub-tiles)
    {
        f32x4 qr[2];
        qr[0] = (f32x4)0.f; qr[1] = (f32x4)0.f;
        #pragma unroll
        for (int sub2 = 0; sub2 < 2; ++sub2) {
            const int tap = sub2 * 16 + c;
            #pragma unroll
            for (int kh = 0; kh < 2; ++kh) {
                unsigned byte = ((unsigned)(tap * 128 + kh * 64 + g * 16))
                              ^ (((unsigned)tap & 7) << 4);
                bf16x8 lb = *(const bf16x8*)(lutkb + byte);
                qr[sub2] = __builtin_amdgcn_mfma_f32_16x16x32_bf16(
                    qa[kh], lb, qr[sub2], 0, 0, 0);
            }
        }
        #pragma unroll
        for (int sub2 = 0; sub2 < 2; ++sub2) {
            const int tap = sub2 * 16 + c;
            if (tap < 17) {
                #pragma unroll
                for (int r = 0; r < 4; ++r)
                    qrelb[(w * 16 + g * 4 + r) * 20 + tap] = (USH)f2b(qr[sub2][r]);
            }
        }
    }
    __syncthreads();   // qsb/lutkb dead; qrelb ready; pb/tapss free

    // hoist tap-0 qrel (pre-scaled by EXPSCALE) for interior tiles
    float qrel0s[4];
    #pragma unroll
    for (int r = 0; r < 4; ++r)
        qrel0s[r] = b2f(qrelb[(w * 16 + g * 4 + r) * 20]) * EXPSCALE;

    f32x4 acc[4];
    #pragma unroll
    for (int dt = 0; dt < 4; ++dt) acc[dt] = (f32x4)0.f;
    float l_r[4];   // per-lane PARTIAL row sums (reduced in epilogue)
    #pragma unroll
    for (int r = 0; r < 4; ++r) l_r[r] = 0.f;

    const int NT = 2 * ib + 2;
    for (int tile = 0; tile < NT; ++tile) {
        const int cur = tile & 1;
        if (tile + 1 < NT)
            stage((tile + 1) << 6, cur ? 0 : 8192, cur ? 16384 : 24576);
        const char* ktb = smem + (cur ? 8192 : 0);
        const char* vtb = smem + (cur ? 24576 : 16384);

        // ---- QK^T ----
        float p[4][4];
        __builtin_amdgcn_s_setprio(1);
        f32x4 s[4];
        #pragma unroll
        for (int sub = 0; sub < 4; ++sub) {
            s[sub] = (f32x4)0.f;
            const int krow = sub * 16 + c;
            #pragma unroll
            for (int kh = 0; kh < 2; ++kh) {
                unsigned byte = ((unsigned)krow << 7) + ((unsigned)kh << 6) + ((unsigned)g << 4);
                byte ^= (unsigned)(krow & 7) << 4;
                bf16x8 kb = *(const bf16x8*)(ktb + byte);
                s[sub] = __builtin_amdgcn_mfma_f32_16x16x32_bf16(qa[kh], kb, s[sub], 0, 0, 0);
            }
        }
        __builtin_amdgcn_s_setprio(0);

        if (tile < NT - 3) {
            // ---- interior fast path: dj <= -65 -> tap index 0 everywhere ----
            #pragma unroll
            for (int sub = 0; sub < 4; ++sub)
                #pragma unroll
                for (int r = 0; r < 4; ++r)
                    p[sub][r] = fast_exp2(s[sub][r] * EXPSCALE + qrel0s[r]);
        } else {
            // ---- boundary: clamped tap lookup + causal mask + tap capture ----
            #pragma unroll
            for (int sub = 0; sub < 4; ++sub) {
                const int dbase = tile * 64 + (sub * 16 + c) - i0 - (w * 16 + g * 4);
                #pragma unroll
                for (int r = 0; r < 4; ++r) {
                    const int dj = dbase - r;
                    int t17 = dj + 16;
                    t17 = t17 < 0 ? 0 : (t17 > 16 ? 16 : t17);
                    const int il = w * 16 + g * 4 + r;
                    float pv = fast_exp2((s[sub][r] + b2f(qrelb[il * 20 + t17])) * EXPSCALE);
                    if (dj > 0) pv = 0.f;
                    p[sub][r] = pv;
                    if (dj >= -15 && dj <= 0)
                        tapss[il * 16 + dj + 15] = pv;
                }
            }
        }

        // ---- accumulate per-lane partial row sums (no cross-lane ops) ----
        #pragma unroll
        for (int r = 0; r < 4; ++r)
            l_r[r] += (p[0][r] + p[1][r]) + (p[2][r] + p[3][r]);

        // ---- P -> per-wave LDS (bf16, swizzled) ----
        char* pw = pb + w * 2048;
        #pragma unroll
        for (int sub = 0; sub < 4; ++sub)
            #pragma unroll
            for (int r = 0; r < 4; ++r) {
                const int row = g * 4 + r;
                unsigned byte = ((unsigned)row << 7) + (((unsigned)(sub * 16 + c)) << 1);
                byte ^= (unsigned)(row & 7) << 4;
                *(short*)(pw + byte) = f2b(p[sub][r]);
            }

        // ---- PV ----
        bf16x8 pa[2];
        #pragma unroll
        for (int jh = 0; jh < 2; ++jh) {
            unsigned byte = ((unsigned)c << 7) + ((unsigned)jh << 6) + ((unsigned)g << 4);
            byte ^= (unsigned)(c & 7) << 4;
            pa[jh] = *(const bf16x8*)(pw + byte);
        }
        __builtin_amdgcn_s_setprio(1);
        #pragma unroll
        for (int dt = 0; dt < 4; ++dt) {
            const int d = dt * 16 + c;
            #pragma unroll
            for (int jh = 0; jh < 2; ++jh) {
                unsigned byte = ((unsigned)d << 7) + ((unsigned)jh << 6) + ((unsigned)g << 4);
                byte ^= (unsigned)(d & 7) << 4;
                bf16x8 vb = *(const bf16x8*)(vtb + byte);
                acc[dt] = __builtin_amdgcn_mfma_f32_16x16x32_bf16(pa[jh], vb, acc[dt], 0, 0, 0);
            }
        }
        __builtin_amdgcn_s_setprio(0);
        __syncthreads();
    }

    // ---- epilogue: reduce row sums, taps + bin-0 residual, write ----
    const int rbase = w * 16 + g * 4;
    #pragma unroll
    for (int r = 0; r < 4; ++r) {
        float lsum = l_r[r];
        #pragma unroll
        for (int msk = 1; msk < 16; msk <<= 1)
            lsum += __shfl_xor(lsum, msk);
        const int il = rbase + r;
        float c0 = lsum;
        float tp[16];
        #pragma unroll
        for (int tap = 0; tap < 16; ++tap) {
            const int jg = i0 + il + tap - 15;
            const float pv = (jg >= 0) ? tapss[il * 16 + tap] : 0.f;
            tp[tap] = pv;
            c0 -= pv;
        }
        const float invl = 1.f / lsum;
        #pragma unroll
        for (int dt = 0; dt < 4; ++dt) {
            const int d = dt * 16 + c;
            float o = acc[dt][r] + c0 * b2f(lvfb[d]);
            #pragma unroll
            for (int tap = 0; tap < 16; ++tap)
                o += tp[tap] * b2f(lvfb[(tap + 1) * 64 + d]);
            o *= invl;
            ao[((size_t)b * S_LEN + (i0 + il)) * D_MODEL + h * DK + d] = (USH)f2b(o);
        }
    }
}

// ---------------------------------------------------------------------------
extern "C" void kernel_launch(void* const* d_in, const int* in_sizes, int n_in,
                              void* d_out, int out_size, void* d_ws, size_t ws_size,
                              hipStream_t stream) {
    const float* x      = (const float*)d_in[0];
    const float* W_attn = (const float*)d_in[1];
    const float* b_attn = (const float*)d_in[2];
    const float* W_proj = (const float*)d_in[3];
    const float* b_proj = (const float*)d_in[4];
    const float* lut_k  = (const float*)d_in[5];
    const float* lut_v  = (const float*)d_in[6];
    float* out = (float*)d_out;

    // workspace layout (all USH)
    USH* qb    = (USH*)d_ws;            // 8M
    USH* kb    = qb + HSZ;              // 8M
    USH* vb    = kb + HSZ;              // 8M (row-major V)
    USH* vtg   = vb + HSZ;              // 8M (per-head transposed V)
    USH* aob   = vtg + HSZ;             // 8M
    USH* xb    = aob + HSZ;             // 8M
    USH* watt  = xb + HSZ;              // 3M
    USH* wproj = watt + 3145728;        // 1M

    // 0) conversions
    conv_bf16_kernel<<<HSZ / (256 * 8), 256, 0, stream>>>(x, xb);
    transp_bf16_kernel<<<dim3(3072 / 64, 1024 / 64), 256, 0, stream>>>(
        W_attn, watt, 1024, 3072);
    transp_bf16_kernel<<<dim3(1024 / 64, 1024 / 64), 256, 0, stream>>>(
        W_proj, wproj, 1024, 1024);

    // 1) QKV projection (bf16 MFMA)
    mfma_gemm_kernel<1><<<dim3(3072 / 128, 8192 / 128), 256, 0, stream>>>(
        xb, watt, b_attn, nullptr, qb, kb, vb, 8192, 3072, 1024);

    // 1b) per-head V transpose
    vtransp_kernel<<<2048, 256, 0, stream>>>(vb, vtg);

    // 2) attention (8 waves x 128 q-rows per block)
    attn_mfma_kernel<<<1024, 512, 0, stream>>>(qb, kb, vtg, lut_k, lut_v, aob);

    // 3) output projection (bf16 MFMA)
    mfma_gemm_kernel<0><<<dim3(1024 / 128, 8192 / 128), 256, 0, stream>>>(
        aob, wproj, b_proj, out, nullptr, nullptr, nullptr, 8192, 1024, 1024);
}